// Round 2
// baseline (480.788 us; speedup 1.0000x reference)
//
#include <hip/hip_runtime.h>
#include <hip/hip_bf16.h>
#include <cstdio>

typedef __attribute__((ext_vector_type(8))) short short8;
typedef __attribute__((ext_vector_type(4))) short short4v;
typedef __attribute__((ext_vector_type(4))) float f32x4;

template <int H> struct VecT;
template <> struct VecT<8> { using T = short8; };
template <> struct VecT<4> { using T = short4v; };

// ---------- bf16 helpers ----------
__device__ __forceinline__ float bfu2f(unsigned short u) {
    return __uint_as_float(((unsigned)u) << 16);
}
__device__ __forceinline__ unsigned short f2bfu(float f) {   // RNE
    __hip_bfloat16 b = __float2bfloat16(f);
    union { __hip_bfloat16 b; unsigned short u; } cv; cv.b = b;
    return cv.u;
}

// ---------- graph/model dims ----------
#define N1 80000
#define N2 16000
#define N3 4096
#define E1 256000
#define E2 65536

// ---------- fused prep: weight splits (frag-major pack) + int zeroing ----------
// Packed layout per matrix: [n16][k32][hi|lo][lane(64)][8] shorts, where
// col = n16*16 + (lane&15), k = k32*32 + (lane>>4)*8 + e. A B-fragment load is
// then 64 lanes x contiguous 16B = 1KB fully coalesced.
__global__ void prep_kernel(const float* __restrict__ W1s, const float* __restrict__ W1d,
                            unsigned short* __restrict__ w1s_pk, unsigned short* __restrict__ w1d_pk,
                            const float* __restrict__ W2s, const float* __restrict__ W2d,
                            unsigned short* __restrict__ w2s_pk, unsigned short* __restrict__ w2d_pk,
                            const float* __restrict__ fW, unsigned short* __restrict__ fw_t3,
                            int* __restrict__ zbase, int zn) {
    int i = blockIdx.x * blockDim.x + threadIdx.x;
    const int S0 = 262144, S1 = 262144, S2 = 8192;
    if (i < S0) {
        const float* W = (i < 131072) ? W1s : W1d;
        unsigned short* pk = (i < 131072) ? w1s_pk : w1d_pk;
        int j = i & 131071;
        int k = j >> 9, n = j & 511;            // [K=256][N=512] row-major, KS=8
        float v = W[j];
        unsigned short hh = f2bfu(v);
        unsigned short ll = f2bfu(v - bfu2f(hh));
        int n16 = n >> 4, l = n & 15, k32 = k >> 5, qq = (k >> 3) & 3, e = k & 7;
        size_t base = ((size_t)(n16 * 8 + k32)) * 1024 + (qq * 16 + l) * 8 + e;
        pk[base] = hh;
        pk[base + 512] = ll;
    } else if (i < S0 + S1) {
        int ii = i - S0;
        const float* W = (ii < 131072) ? W2s : W2d;
        unsigned short* pk = (ii < 131072) ? w2s_pk : w2d_pk;
        int j = ii & 131071;
        int k = j >> 8, n = j & 255;            // [K=512][N=256] row-major, KS=16
        float v = W[j];
        unsigned short hh = f2bfu(v);
        unsigned short ll = f2bfu(v - bfu2f(hh));
        int n16 = n >> 4, l = n & 15, k32 = k >> 5, qq = (k >> 3) & 3, e = k & 7;
        size_t base = ((size_t)(n16 * 16 + k32)) * 1024 + (qq * 16 + l) * 8 + e;
        pk[base] = hh;
        pk[base + 512] = ll;
    } else if (i < S0 + S1 + S2) {
        int j = i - S0 - S1;
        int k = j >> 6, n = j & 63;             // K=128, N=64
        float v = fW[j];
        unsigned short h = f2bfu(v);
        unsigned short l = f2bfu(v - bfu2f(h));
        size_t base = (size_t)n * 384;
        fw_t3[base + k] = h;
        fw_t3[base + 128 + k] = l;
        fw_t3[base + 256 + k] = h;
    } else {
        int j = i - S0 - S1 - S2;
        if (j < zn) zbase[j] = 0;
    }
}

// ---------- CSR build (both graphs per launch) ----------
__global__ void hist_dual(const int* __restrict__ d1, int* __restrict__ c1,
                          const int* __restrict__ d2, int* __restrict__ c2) {
    int i = blockIdx.x * blockDim.x + threadIdx.x;
    if (i < E1) {
        int d = d1[i];
        if ((unsigned)d < (unsigned)N2) atomicAdd(&c1[d], 1);
    } else if (i < E1 + E2) {
        int d = d2[i - E1];
        if ((unsigned)d < (unsigned)N3) atomicAdd(&c2[d], 1);
    }
}
__global__ __launch_bounds__(1024)
void scan_dual(const int* __restrict__ c1, int* __restrict__ s1, int Nd1,
               const int* __restrict__ c2, int* __restrict__ s2, int Nd2) {
    const int* cnt = (blockIdx.x == 0) ? c1 : c2;
    int* start = (blockIdx.x == 0) ? s1 : s2;
    int Nd = (blockIdx.x == 0) ? Nd1 : Nd2;
    __shared__ int part[1024];
    int t = threadIdx.x;
    int k = (Nd + 1023) >> 10;
    int lo = t * k, hi = min(lo + k, Nd);
    if (lo > Nd) lo = Nd;
    int s = 0;
    for (int i = lo; i < hi; i++) s += cnt[i];
    part[t] = s;
    __syncthreads();
    for (int off = 1; off < 1024; off <<= 1) {
        int v = (t >= off) ? part[t - off] : 0;
        __syncthreads();
        part[t] += v;
        __syncthreads();
    }
    int run = (t > 0) ? part[t - 1] : 0;
    for (int i = lo; i < hi; i++) { start[i] = run; run += cnt[i]; }
    if (t == 1023) start[Nd] = part[1023];
}
__global__ void fill_dual(const int* __restrict__ sa1, const int* __restrict__ da1,
                          const int* __restrict__ st1, int* __restrict__ cu1, int* __restrict__ cs1,
                          const int* __restrict__ sa2, const int* __restrict__ da2,
                          const int* __restrict__ st2, int* __restrict__ cu2, int* __restrict__ cs2) {
    int i = blockIdx.x * blockDim.x + threadIdx.x;
    const int *sa, *da, *st;
    int *cu, *cs;
    int Nd, Ns, e;
    if (i < E1) { sa = sa1; da = da1; st = st1; cu = cu1; cs = cs1; Nd = N2; Ns = N1; e = i; }
    else if (i < E1 + E2) { sa = sa2; da = da2; st = st2; cu = cu2; cs = cs2; Nd = N3; Ns = N2; e = i - E1; }
    else return;
    int d = da[e];
    if ((unsigned)d >= (unsigned)Nd) return;
    int p = atomicAdd(&cu[d], 1);
    int idx = st[d] + p;
    if (idx >= st[d + 1]) return;
    int s = sa[e];
    if ((unsigned)s >= (unsigned)Ns) s = 0;
    cs[idx] = s;
}

// ---------- STREAMING MFMA GEMM: no LDS, no barriers; per-wave software pipeline ----------
// Each wave owns 64 rows x 64 cols. A loaded global->reg in fragment shape (fp32),
// split hi/lo bf16 in regs. B read from frag-major packed layout (L2-resident, coalesced).
// A(t+1) issued before MFMAs of step t; B frags reloaded for t+1 after last use.
// 1-D grid with XCD swizzle: all N-blocks of an M-panel land on the same XCD so A is
// fetched from HBM once and shared via that XCD's L2.
// Fused escore epilogue: es[row, head] = sum_c C_f32[row, head*64+c]*att[head*64+c].
__device__ __forceinline__ void convA(const float4* v, short8* ah, short8* al) {
#pragma unroll
    for (int rg = 0; rg < 4; rg++) {
        float va[8] = {v[2*rg].x, v[2*rg].y, v[2*rg].z, v[2*rg].w,
                       v[2*rg+1].x, v[2*rg+1].y, v[2*rg+1].z, v[2*rg+1].w};
        short8 h8, l8;
#pragma unroll
        for (int j = 0; j < 8; j++) {
            unsigned short hh = f2bfu(va[j]);
            h8[j] = (short)hh;
            l8[j] = (short)f2bfu(va[j] - bfu2f(hh));
        }
        ah[rg] = h8; al[rg] = l8;
    }
}

__global__ __launch_bounds__(256, 2)
void gemm_stream(const float* __restrict__ A,
                 const unsigned short* __restrict__ Bp1, unsigned short* __restrict__ C1,
                 const float* __restrict__ att1, float* __restrict__ es1,
                 const unsigned short* __restrict__ Bp2, unsigned short* __restrict__ C2,
                 const float* __restrict__ att2, float* __restrict__ es2,
                 int Mb1, int MT, int NB, int N, int K, int H) {
    // XCD swizzle: hw round-robins blockIdx over 8 XCDs; map so the NB column-blocks
    // of one M-panel get consecutive per-XCD slots (same XCD, adjacent in time).
    const int h = blockIdx.x;
    const int xcd = h & 7;
    const int s = h >> 3;
    const int mt = (s / NB) * 8 + xcd;
    const int nb = s % NB;
    if (mt >= MT) return;
    const unsigned short* Bp; unsigned short* C; const float* att; float* es_out;
    int m0;
    if (mt < Mb1) { Bp = Bp1; C = C1; att = att1; es_out = es1; m0 = mt * 64; }
    else          { Bp = Bp2; C = C2; att = att2; es_out = es2; m0 = (mt - Mb1) * 64; }
    const int tid = threadIdx.x;
    const int wave = tid >> 6, lane = tid & 63;
    const int q = lane >> 4, l15 = lane & 15;
    const int n0 = nb * 256 + wave * 64;
    const int KS = K >> 5;
    const float* Arow = A + (size_t)(m0 + l15) * K + q * 8;
    const unsigned short* Bbase = Bp + (size_t)(n0 >> 4) * KS * 1024 + lane * 8;

    f32x4 acc[4][4] = {};
    float4 vA[8], vB[8];
    short8 bh[4], bl[4];

    auto issueA = [&](int k0, float4* v) {
#pragma unroll
        for (int rg = 0; rg < 4; rg++) {
            const float* p = Arow + (size_t)rg * 16 * K + k0;
            v[2*rg]   = *(const float4*)p;
            v[2*rg+1] = *(const float4*)(p + 4);
        }
    };
    auto loadB = [&](int k32, int nt, short8& h8, short8& l8) {
        const unsigned short* p = Bbase + ((size_t)nt * KS + k32) * 1024;
        h8 = *(const short8*)p;
        l8 = *(const short8*)(p + 512);
    };
    auto mstep = [&](float4* v, int tn) {
        short8 ah[4], al[4];
        convA(v, ah, al);
#pragma unroll
        for (int nt = 0; nt < 4; nt++) {
#pragma unroll
            for (int rg = 0; rg < 4; rg++) {
                acc[rg][nt] = __builtin_amdgcn_mfma_f32_16x16x32_bf16(ah[rg], bh[nt], acc[rg][nt], 0, 0, 0);
                acc[rg][nt] = __builtin_amdgcn_mfma_f32_16x16x32_bf16(ah[rg], bl[nt], acc[rg][nt], 0, 0, 0);
                acc[rg][nt] = __builtin_amdgcn_mfma_f32_16x16x32_bf16(al[rg], bh[nt], acc[rg][nt], 0, 0, 0);
            }
            if (tn >= 0) loadB(tn, nt, bh[nt], bl[nt]);   // prefetch B frag for step tn
        }
    };

    // prologue: A0 + B0 in flight
    issueA(0, vA);
#pragma unroll
    for (int nt = 0; nt < 4; nt++) loadB(0, nt, bh[nt], bl[nt]);

    for (int t = 0; t < KS; t += 2) {
        if (t + 1 < KS) issueA((t + 1) << 5, vB);
        mstep(vA, (t + 1 < KS) ? t + 1 : -1);
        if (t + 1 < KS) {
            if (t + 2 < KS) issueA((t + 2) << 5, vA);
            mstep(vB, (t + 2 < KS) ? t + 2 : -1);
        }
    }

    // epilogue: C store (bf16)
#pragma unroll
    for (int rg = 0; rg < 4; rg++)
#pragma unroll
        for (int nt = 0; nt < 4; nt++)
#pragma unroll
            for (int r = 0; r < 4; r++) {
                int row = m0 + rg * 16 + q * 4 + r;
                int col = n0 + nt * 16 + l15;
                C[(size_t)row * N + col] = f2bfu(acc[rg][nt][r]);
            }
    // fused escore (wave owns exactly one head's 64 cols)
    {
        const int head = n0 >> 6;
        float av[4];
#pragma unroll
        for (int nt = 0; nt < 4; nt++) av[nt] = att[head * 64 + nt * 16 + l15];
#pragma unroll
        for (int rg = 0; rg < 4; rg++)
#pragma unroll
            for (int r = 0; r < 4; r++) {
                float p = acc[rg][0][r] * av[0] + acc[rg][1][r] * av[1]
                        + acc[rg][2][r] * av[2] + acc[rg][3][r] * av[3];
#pragma unroll
                for (int off = 1; off < 16; off <<= 1) p += __shfl_xor(p, off);
                if (l15 == 0)
                    es_out[(size_t)(m0 + rg * 16 + q * 4 + r) * H + head] = p;
            }
    }
}

// ---------- small MFMA GEMM (64x64 tile, Bt3 layout, fp32 A in-kernel split) — flat only ----------
__global__ __launch_bounds__(256)
void gemm_mfma(const float* __restrict__ A, const unsigned short* __restrict__ Bt3,
               float* __restrict__ C, int M, int N, int K) {
    const int KK = 3 * K;
    __shared__ unsigned short As[2][64][72];
    __shared__ unsigned short Bs[64][72];
    const int tid = threadIdx.x;
    const int wave = tid >> 6, lane = tid & 63;
    const int wr = wave >> 1, wc = wave & 1;
    const int quad = lane >> 4, l15 = lane & 15;
    const int m0 = blockIdx.y * 64, n0 = blockIdx.x * 64;
    f32x4 acc[2][2] = {};
    for (int k0 = 0; k0 < KK; k0 += 64) {
        const int seg = k0 / K;
        const int ks = k0 - seg * K;
#pragma unroll
        for (int i = 0; i < 2; i++) {
            int idx = tid + i * 256;
            int r = idx >> 3, cv = (idx & 7) * 8;
            const float* ap = &A[(size_t)(m0 + r) * K + ks + cv];
            const float4 v0 = *(const float4*)ap;
            const float4 v1 = *(const float4*)(ap + 4);
            float va[8] = {v0.x, v0.y, v0.z, v0.w, v1.x, v1.y, v1.z, v1.w};
            short8 h8, l8;
#pragma unroll
            for (int j = 0; j < 8; j++) {
                unsigned short hh = f2bfu(va[j]);
                h8[j] = (short)hh;
                l8[j] = (short)f2bfu(va[j] - bfu2f(hh));
            }
            *(short8*)&As[0][r][cv] = h8;
            *(short8*)&As[1][r][cv] = l8;
            *(short8*)&Bs[r][cv] = *(const short8*)&Bt3[(size_t)(n0 + r) * KK + k0 + cv];
        }
        __syncthreads();
        const int abank = (seg < 2) ? 0 : 1;
#pragma unroll
        for (int kk = 0; kk < 64; kk += 32) {
            short8 a[2], b[2];
#pragma unroll
            for (int t = 0; t < 2; t++) {
                a[t] = *(const short8*)&As[abank][wr * 32 + t * 16 + l15][kk + quad * 8];
                b[t] = *(const short8*)&Bs[wc * 32 + t * 16 + l15][kk + quad * 8];
            }
#pragma unroll
            for (int mt = 0; mt < 2; mt++)
#pragma unroll
                for (int nt = 0; nt < 2; nt++)
                    acc[mt][nt] = __builtin_amdgcn_mfma_f32_16x16x32_bf16(
                        a[mt], b[nt], acc[mt][nt], 0, 0, 0);
        }
        __syncthreads();
    }
#pragma unroll
    for (int mt = 0; mt < 2; mt++)
#pragma unroll
        for (int nt = 0; nt < 2; nt++)
#pragma unroll
            for (int r = 0; r < 4; r++) {
                int row = m0 + wr * 32 + mt * 16 + quad * 4 + r;
                int col = n0 + wc * 32 + nt * 16 + l15;
                C[(size_t)row * N + col] = acc[mt][nt][r];
            }
}

// ---------- GAT aggregate: one WAVE per dst node, all heads; coalesced row gathers ----------
template <int H, bool ELU>
__global__ __launch_bounds__(256)
void gat_agg2(const int* __restrict__ csr, const int* __restrict__ rs,
              const unsigned short* __restrict__ hs,  // [Ns, H*64] bf16
              const float* __restrict__ es,           // [Ns, H]
              const float* __restrict__ ed,           // [Nd, H]
              const float* __restrict__ bias,         // [H*64] or null
              float* __restrict__ out,                // [Nd, H*64] fp32
              int Nd) {
    constexpr int LH = (H == 8) ? 3 : 2;
    constexpr int EPC = 64 >> LH;
    const int lane = threadIdx.x & 63;
    const int d = blockIdx.x * (blockDim.x >> 6) + (threadIdx.x >> 6);
    if (d >= Nd) return;
    const int beg = rs[d];
    const int deg = rs[d + 1] - beg;
    const int n = deg + 1;
    const int h = lane & (H - 1);
    const int e0 = lane >> LH;
    const float edh = ed[(size_t)d * H + h];
    float mx = -1e30f;
    for (int j0 = 0; j0 < n; j0 += EPC) {
        int j = j0 + e0;
        if (j < n) {
            int s = (j < deg) ? csr[beg + j] : d;
            float a = es[(size_t)s * H + h] + edh;
            a = (a > 0.0f) ? a : 0.2f * a;
            mx = fmaxf(mx, a);
        }
    }
#pragma unroll
    for (int off = H; off < 64; off <<= 1) mx = fmaxf(mx, __shfl_xor(mx, off));
    float den = 0.0f;
    for (int j0 = 0; j0 < n; j0 += EPC) {
        int j = j0 + e0;
        if (j < n) {
            int s = (j < deg) ? csr[beg + j] : d;
            float a = es[(size_t)s * H + h] + edh;
            a = (a > 0.0f) ? a : 0.2f * a;
            den += expf(a - mx);
        }
    }
#pragma unroll
    for (int off = H; off < 64; off <<= 1) den += __shfl_xor(den, off);
    const float inv = 1.0f / den;
    const int hB = lane >> (6 - LH);
    const float mB = __shfl(mx, hB);
    const float invB = __shfl(inv, hB);
    const float edhB = __shfl(edh, hB);
    using V = typename VecT<H>::T;
    float acc[H] = {};
    const size_t rowoff = (size_t)lane * H;
    int j = 0;
    for (; j + 4 <= n; j += 4) {
        int s[4]; V rv[4]; float w[4];
#pragma unroll
        for (int u = 0; u < 4; u++) { int jj = j + u; s[u] = (jj < deg) ? csr[beg + jj] : d; }
#pragma unroll
        for (int u = 0; u < 4; u++) rv[u] = *(const V*)&hs[(size_t)s[u] * (H * 64) + rowoff];
#pragma unroll
        for (int u = 0; u < 4; u++) {
            float a = es[(size_t)s[u] * H + hB] + edhB;
            a = (a > 0.0f) ? a : 0.2f * a;
            w[u] = expf(a - mB) * invB;
        }
#pragma unroll
        for (int u = 0; u < 4; u++)
#pragma unroll
            for (int k = 0; k < H; k++) acc[k] += w[u] * bfu2f((unsigned short)rv[u][k]);
    }
    for (; j < n; j++) {
        int s = (j < deg) ? csr[beg + j] : d;
        V rv = *(const V*)&hs[(size_t)s * (H * 64) + rowoff];
        float a = es[(size_t)s * H + hB] + edhB;
        a = (a > 0.0f) ? a : 0.2f * a;
        float w = expf(a - mB) * invB;
#pragma unroll
        for (int k = 0; k < H; k++) acc[k] += w * bfu2f((unsigned short)rv[k]);
    }
#pragma unroll
    for (int k = 0; k < H; k++) {
        float v = acc[k];
        if (ELU) {
            v += bias[lane * H + k];
            v = (v > 0.0f) ? v : expm1f(v);
        }
        acc[k] = v;
    }
    float* op = out + (size_t)d * (H * 64) + rowoff;
#pragma unroll
    for (int q = 0; q < H / 4; q++)
        *(float4*)&op[q * 4] = *(float4*)&acc[q * 4];
}

// ---------- final ----------
__global__ void final_kernel(const float* __restrict__ acc2, const float* __restrict__ bias2,
                             const float* __restrict__ fbuf, const float* __restrict__ flat_b,
                             const float* __restrict__ last, const float* __restrict__ outW,
                             const float* __restrict__ outb, float* __restrict__ out, int N) {
    int n = blockIdx.x * blockDim.x + threadIdx.x;
    if (n >= N) return;
    float s = outb[0];
    const float* a = acc2 + (size_t)n * 256;
    for (int c = 0; c < 64; c++) {
        float h2 = 0.25f * (a[c] + a[64 + c] + a[128 + c] + a[192 + c]) + bias2[c];
        s += h2 * outW[c];
        s += (fbuf[(size_t)n * 64 + c] + flat_b[c]) * outW[64 + c];
        s += last[(size_t)n * 64 + c] * outW[128 + c];
    }
    out[n] = s;
}

extern "C" void kernel_launch(void* const* d_in, const int* in_sizes, int n_in,
                              void* d_out, int out_size, void* d_ws, size_t ws_size,
                              hipStream_t stream) {
    const float* x    = (const float*)d_in[0];
    const float* flat = (const float*)d_in[1];
    const float* last = (const float*)d_in[2];
    const int*  es1i  = (const int*)d_in[3];
    const int*  ed1i  = (const int*)d_in[4];
    const int*  es2i  = (const int*)d_in[5];
    const int*  ed2i  = (const int*)d_in[6];
    const float* W1s  = (const float*)d_in[7];
    const float* W1d  = (const float*)d_in[8];
    const float* a1s  = (const float*)d_in[9];
    const float* a1d  = (const float*)d_in[10];
    const float* b1   = (const float*)d_in[11];
    const float* W2s  = (const float*)d_in[12];
    const float* W2d  = (const float*)d_in[13];
    const float* a2s  = (const float*)d_in[14];
    const float* a2d  = (const float*)d_in[15];
    const float* b2   = (const float*)d_in[16];
    const float* fW   = (const float*)d_in[17];
    const float* fb   = (const float*)d_in[18];
    const float* oW   = (const float*)d_in[19];
    const float* ob   = (const float*)d_in[20];
    float* out = (float*)d_out;

    float* ws = (float*)d_ws;
    // ---- layout (float-element offsets; proven footprint) ----
    unsigned short* hs1_bf = (unsigned short*)ws;                  // 40,960,000 us
    unsigned short* hd1_bf = (unsigned short*)(ws + 20480000);     //  8,192,000 us
    float* es1f = ws + 24576000;                                   // 640,000
    float* ed1f = ws + 25216000;                                   // 128,000
    float* acc1 = ws + 25344000;                                   // 8,192,000 -> 33,536,000
    unsigned short* wb = (unsigned short*)(ws + 54016000);
    unsigned short* w1s_pk = wb;                                   // 262144 us each
    unsigned short* w1d_pk = wb + 262144;
    unsigned short* w2s_pk = wb + 524288;
    unsigned short* w2d_pk = wb + 786432;
    unsigned short* fw_t3  = wb + 1048576;
    int* ibase   = (int*)(ws + 54816000);
    int* cnt1    = ibase;
    int* cursor1 = ibase + 16000;
    int* cnt2    = ibase + 32000;
    int* cursor2 = ibase + 36096;
    int* start1  = ibase + 40192;
    int* start2  = ibase + 56193;
    int* csr1    = ibase + 60290;
    int* csr2    = ibase + 316290;
    const size_t NEED = ((size_t)54816000 + 381826) * 4;
    if (ws_size < NEED) {
        fprintf(stderr, "kernel_launch: ws_size %zu < needed %zu\n", ws_size, NEED);
        return;
    }
    unsigned short* hs2_bf = (unsigned short*)ws;
    unsigned short* hd2_bf = (unsigned short*)(ws + 2048000);
    float* es2f = ws + 2572288;
    float* ed2f = ws + 2636288;
    float* acc2 = ws + 2652672;
    float* fbuf = ws + 3701248;

    // ---- prep (1 launch) + CSR build (3 launches) ----
    {
        int total = 262144 + 262144 + 8192 + 40192;
        prep_kernel<<<(total + 255) / 256, 256, 0, stream>>>(
            W1s, W1d, w1s_pk, w1d_pk,
            W2s, W2d, w2s_pk, w2d_pk,
            fW, fw_t3, ibase, 40192);
    }
    hist_dual<<<(E1 + E2 + 255) / 256, 256, 0, stream>>>(ed1i, cnt1, ed2i, cnt2);
    scan_dual<<<2, 1024, 0, stream>>>(cnt1, start1, N2, cnt2, start2, N3);
    fill_dual<<<(E1 + E2 + 255) / 256, 256, 0, stream>>>(
        es1i, ed1i, start1, cursor1, csr1, es2i, ed2i, start2, cursor2, csr2);

    // ---- layer 1: src+dst GEMMs in one grid (streaming, barrier-free) ----
    {
        const int MT = N1 / 64 + N2 / 64;   // 1250 + 250 = 1500 M-panels
        const int NB = 512 / 256;           // 2 column-blocks
        const int grid = 8 * NB * ((MT + 7) / 8);
        gemm_stream<<<grid, 256, 0, stream>>>(
            x, w1s_pk, hs1_bf, a1s, es1f,
            w1d_pk, hd1_bf, a1d, ed1f,
            N1 / 64, MT, NB, 512, 256, 8);
    }
    gat_agg2<8, true><<<N2 / 4, 256, 0, stream>>>(csr1, start1, hs1_bf, es1f, ed1f, b1, acc1, N2);

    // ---- layer 2: src+dst GEMMs in one grid ----
    {
        const int MT = N2 / 64 + N3 / 64;   // 250 + 64 = 314
        const int NB = 1;
        const int grid = 8 * NB * ((MT + 7) / 8);
        gemm_stream<<<grid, 256, 0, stream>>>(
            acc1, w2s_pk, hs2_bf, a2s, es2f,
            w2d_pk, hd2_bf, a2d, ed2f,
            N2 / 64, MT, NB, 256, 512, 4);
    }
    gat_agg2<4, false><<<N3 / 4, 256, 0, stream>>>(csr2, start2, hs2_bf, es2f, ed2f, nullptr, acc2, N3);

    // ---- flat MLP + output ----
    gemm_mfma<<<dim3(1, N3 / 64), 256, 0, stream>>>(flat, fw_t3, fbuf, N3, 64, 128);
    final_kernel<<<(N3 + 255) / 256, 256, 0, stream>>>(acc2, b2, fbuf, fb, last, oW, ob, out, N3);
}

// Round 3
// 462.926 us; speedup vs baseline: 1.0386x; 1.0386x over previous
//
#include <hip/hip_runtime.h>
#include <hip/hip_bf16.h>
#include <cstdio>

typedef __attribute__((ext_vector_type(8))) short short8;
typedef __attribute__((ext_vector_type(4))) short short4v;
typedef __attribute__((ext_vector_type(8))) _Float16 half8;
typedef __attribute__((ext_vector_type(4))) float f32x4;

template <int H> struct VecT;
template <> struct VecT<8> { using T = short8; };
template <> struct VecT<4> { using T = short4v; };

// ---------- bf16/fp16 helpers ----------
__device__ __forceinline__ float bfu2f(unsigned short u) {
    return __uint_as_float(((unsigned)u) << 16);
}
__device__ __forceinline__ unsigned short f2bfu(float f) {   // RNE
    __hip_bfloat16 b = __float2bfloat16(f);
    union { __hip_bfloat16 b; unsigned short u; } cv; cv.b = b;
    return cv.u;
}
__device__ __forceinline__ unsigned short f2hu(float f) {    // fp16 RNE bits
    _Float16 h = (_Float16)f;
    union { _Float16 h; unsigned short u; } cv; cv.h = h;
    return cv.u;
}

// ---------- graph/model dims ----------
#define N1 80000
#define N2 16000
#define N3 4096
#define E1 256000
#define E2 65536

// ---------- fused prep: weight fp16 frag-major pack + flat Bt3 + int zeroing ----------
// Packed layout per matrix: [n16][k32][lane(64)][8] f16 bits, where
// col = n16*16 + (lane&15), k = k32*32 + (lane>>4)*8 + e. A B-fragment load is
// then 64 lanes x contiguous 16B = 1KB fully coalesced, single MFMA operand.
__global__ void prep_kernel(const float* __restrict__ W1s, const float* __restrict__ W1d,
                            unsigned short* __restrict__ w1s_pk, unsigned short* __restrict__ w1d_pk,
                            const float* __restrict__ W2s, const float* __restrict__ W2d,
                            unsigned short* __restrict__ w2s_pk, unsigned short* __restrict__ w2d_pk,
                            const float* __restrict__ fW, unsigned short* __restrict__ fw_t3,
                            int* __restrict__ zbase, int zn) {
    int i = blockIdx.x * blockDim.x + threadIdx.x;
    const int S0 = 262144, S1 = 262144, S2 = 8192;
    if (i < S0) {
        const float* W = (i < 131072) ? W1s : W1d;
        unsigned short* pk = (i < 131072) ? w1s_pk : w1d_pk;
        int j = i & 131071;
        int k = j >> 9, n = j & 511;            // [K=256][N=512] row-major, KS=8
        int n16 = n >> 4, l = n & 15, k32 = k >> 5, qq = (k >> 3) & 3, e = k & 7;
        size_t base = ((size_t)(n16 * 8 + k32)) * 512 + (qq * 16 + l) * 8 + e;
        pk[base] = f2hu(W[j]);
    } else if (i < S0 + S1) {
        int ii = i - S0;
        const float* W = (ii < 131072) ? W2s : W2d;
        unsigned short* pk = (ii < 131072) ? w2s_pk : w2d_pk;
        int j = ii & 131071;
        int k = j >> 8, n = j & 255;            // [K=512][N=256] row-major, KS=16
        int n16 = n >> 4, l = n & 15, k32 = k >> 5, qq = (k >> 3) & 3, e = k & 7;
        size_t base = ((size_t)(n16 * 16 + k32)) * 512 + (qq * 16 + l) * 8 + e;
        pk[base] = f2hu(W[j]);
    } else if (i < S0 + S1 + S2) {
        int j = i - S0 - S1;
        int k = j >> 6, n = j & 63;             // K=128, N=64 (flat MLP, bf16 hi/lo trick)
        float v = fW[j];
        unsigned short h = f2bfu(v);
        unsigned short l = f2bfu(v - bfu2f(h));
        size_t base = (size_t)n * 384;
        fw_t3[base + k] = h;
        fw_t3[base + 128 + k] = l;
        fw_t3[base + 256 + k] = h;
    } else {
        int j = i - S0 - S1 - S2;
        if (j < zn) zbase[j] = 0;
    }
}

// ---------- CSR build (both graphs per launch) ----------
__global__ void hist_dual(const int* __restrict__ d1, int* __restrict__ c1,
                          const int* __restrict__ d2, int* __restrict__ c2) {
    int i = blockIdx.x * blockDim.x + threadIdx.x;
    if (i < E1) {
        int d = d1[i];
        if ((unsigned)d < (unsigned)N2) atomicAdd(&c1[d], 1);
    } else if (i < E1 + E2) {
        int d = d2[i - E1];
        if ((unsigned)d < (unsigned)N3) atomicAdd(&c2[d], 1);
    }
}
__global__ __launch_bounds__(1024)
void scan_dual(const int* __restrict__ c1, int* __restrict__ s1, int Nd1,
               const int* __restrict__ c2, int* __restrict__ s2, int Nd2) {
    const int* cnt = (blockIdx.x == 0) ? c1 : c2;
    int* start = (blockIdx.x == 0) ? s1 : s2;
    int Nd = (blockIdx.x == 0) ? Nd1 : Nd2;
    __shared__ int part[1024];
    int t = threadIdx.x;
    int k = (Nd + 1023) >> 10;
    int lo = t * k, hi = min(lo + k, Nd);
    if (lo > Nd) lo = Nd;
    int s = 0;
    for (int i = lo; i < hi; i++) s += cnt[i];
    part[t] = s;
    __syncthreads();
    for (int off = 1; off < 1024; off <<= 1) {
        int v = (t >= off) ? part[t - off] : 0;
        __syncthreads();
        part[t] += v;
        __syncthreads();
    }
    int run = (t > 0) ? part[t - 1] : 0;
    for (int i = lo; i < hi; i++) { start[i] = run; run += cnt[i]; }
    if (t == 1023) start[Nd] = part[1023];
}
__global__ void fill_dual(const int* __restrict__ sa1, const int* __restrict__ da1,
                          const int* __restrict__ st1, int* __restrict__ cu1, int* __restrict__ cs1,
                          const int* __restrict__ sa2, const int* __restrict__ da2,
                          const int* __restrict__ st2, int* __restrict__ cu2, int* __restrict__ cs2) {
    int i = blockIdx.x * blockDim.x + threadIdx.x;
    const int *sa, *da, *st;
    int *cu, *cs;
    int Nd, Ns, e;
    if (i < E1) { sa = sa1; da = da1; st = st1; cu = cu1; cs = cs1; Nd = N2; Ns = N1; e = i; }
    else if (i < E1 + E2) { sa = sa2; da = da2; st = st2; cu = cu2; cs = cs2; Nd = N3; Ns = N2; e = i - E1; }
    else return;
    int d = da[e];
    if ((unsigned)d >= (unsigned)Nd) return;
    int p = atomicAdd(&cu[d], 1);
    int idx = st[d] + p;
    if (idx >= st[d + 1]) return;
    int s = sa[e];
    if ((unsigned)s >= (unsigned)Ns) s = 0;
    cs[idx] = s;
}

// ---------- STREAMING fp16 MFMA GEMM: no LDS, no barriers; 3-deep A prefetch ----------
// Single-pass fp16 (error ~4e-4 << bf16 C-store quantization 2^-7 that dominates absmax).
// Each wave owns 64 rows x 64 cols. A fp32 global->reg (frag shape), cvt f16 in regs.
// B read from fp16 frag-major pack (L2-resident, one 16B/lane load per fragment).
// A(t+2) in flight while computing step t; B(t+1) loaded after last use in step t.
// 1-D grid with XCD swizzle: all N-blocks of an M-panel land on the same XCD.
// Fused escore epilogue: es[row, head] = sum_c C_f32[row, head*64+c]*att[head*64+c].
__device__ __forceinline__ void convA16(const float4* v, half8* a) {
#pragma unroll
    for (int rg = 0; rg < 4; rg++) {
        float va[8] = {v[2*rg].x, v[2*rg].y, v[2*rg].z, v[2*rg].w,
                       v[2*rg+1].x, v[2*rg+1].y, v[2*rg+1].z, v[2*rg+1].w};
        half8 h;
#pragma unroll
        for (int j = 0; j < 8; j++) h[j] = (_Float16)va[j];
        a[rg] = h;
    }
}

__global__ __launch_bounds__(256, 2)
void gemm_stream(const float* __restrict__ A,
                 const unsigned short* __restrict__ Bp1, unsigned short* __restrict__ C1,
                 const float* __restrict__ att1, float* __restrict__ es1,
                 const unsigned short* __restrict__ Bp2, unsigned short* __restrict__ C2,
                 const float* __restrict__ att2, float* __restrict__ es2,
                 int Mb1, int MT, int NB, int N, int K, int H) {
    // XCD swizzle: hw round-robins blockIdx over 8 XCDs; map so the NB column-blocks
    // of one M-panel get consecutive per-XCD slots (same XCD, adjacent in time).
    const int hb = blockIdx.x;
    const int xcd = hb & 7;
    const int s = hb >> 3;
    const int mt = (s / NB) * 8 + xcd;
    const int nb = s % NB;
    if (mt >= MT) return;
    const unsigned short* Bp; unsigned short* C; const float* att; float* es_out;
    int m0;
    if (mt < Mb1) { Bp = Bp1; C = C1; att = att1; es_out = es1; m0 = mt * 64; }
    else          { Bp = Bp2; C = C2; att = att2; es_out = es2; m0 = (mt - Mb1) * 64; }
    const int tid = threadIdx.x;
    const int wave = tid >> 6, lane = tid & 63;
    const int q = lane >> 4, l15 = lane & 15;
    const int n0 = nb * 256 + wave * 64;
    const int KS = K >> 5;
    const float* Arow = A + (size_t)(m0 + l15) * K + q * 8;
    const unsigned short* Bbase = Bp + (size_t)(n0 >> 4) * KS * 512 + lane * 8;

    f32x4 acc[4][4] = {};
    float4 vA[8], vB[8], vC[8];
    half8 b[4];

    auto issueA = [&](int k0, float4* v) {
#pragma unroll
        for (int rg = 0; rg < 4; rg++) {
            const float* p = Arow + (size_t)rg * 16 * K + k0;
            v[2*rg]   = *(const float4*)p;
            v[2*rg+1] = *(const float4*)(p + 4);
        }
    };
    auto loadB = [&](int k32, int nt, half8& hb8) {
        hb8 = *(const half8*)(Bbase + ((size_t)nt * KS + k32) * 512);
    };
    auto mstep = [&](float4* v, int tn) {
        half8 a[4];
        convA16(v, a);
#pragma unroll
        for (int nt = 0; nt < 4; nt++) {
#pragma unroll
            for (int rg = 0; rg < 4; rg++)
                acc[rg][nt] = __builtin_amdgcn_mfma_f32_16x16x32_f16(a[rg], b[nt], acc[rg][nt], 0, 0, 0);
            if (tn >= 0) loadB(tn, nt, b[nt]);   // prefetch B frag for step tn
        }
    };

    // prologue: A0, A1 and B0 in flight
    issueA(0, vA);
#pragma unroll
    for (int nt = 0; nt < 4; nt++) loadB(0, nt, b[nt]);
    if (KS > 1) issueA(1 << 5, vB);

    for (int t = 0; t < KS; t += 3) {
        if (t + 2 < KS) issueA((t + 2) << 5, vC);
        mstep(vA, (t + 1 < KS) ? t + 1 : -1);
        if (t + 1 < KS) {
            if (t + 3 < KS) issueA((t + 3) << 5, vA);
            mstep(vB, (t + 2 < KS) ? t + 2 : -1);
        }
        if (t + 2 < KS) {
            if (t + 4 < KS) issueA((t + 4) << 5, vB);
            mstep(vC, (t + 3 < KS) ? t + 3 : -1);
        }
    }

    // epilogue: C store (bf16)
#pragma unroll
    for (int rg = 0; rg < 4; rg++)
#pragma unroll
        for (int nt = 0; nt < 4; nt++)
#pragma unroll
            for (int r = 0; r < 4; r++) {
                int row = m0 + rg * 16 + q * 4 + r;
                int col = n0 + nt * 16 + l15;
                C[(size_t)row * N + col] = f2bfu(acc[rg][nt][r]);
            }
    // fused escore (wave owns exactly one head's 64 cols)
    {
        const int head = n0 >> 6;
        float av[4];
#pragma unroll
        for (int nt = 0; nt < 4; nt++) av[nt] = att[head * 64 + nt * 16 + l15];
#pragma unroll
        for (int rg = 0; rg < 4; rg++)
#pragma unroll
            for (int r = 0; r < 4; r++) {
                float p = acc[rg][0][r] * av[0] + acc[rg][1][r] * av[1]
                        + acc[rg][2][r] * av[2] + acc[rg][3][r] * av[3];
#pragma unroll
                for (int off = 1; off < 16; off <<= 1) p += __shfl_xor(p, off);
                if (l15 == 0)
                    es_out[(size_t)(m0 + rg * 16 + q * 4 + r) * H + head] = p;
            }
    }
}

// ---------- small MFMA GEMM (64x64 tile, Bt3 layout, fp32 A in-kernel split) — flat only ----------
__global__ __launch_bounds__(256)
void gemm_mfma(const float* __restrict__ A, const unsigned short* __restrict__ Bt3,
               float* __restrict__ C, int M, int N, int K) {
    const int KK = 3 * K;
    __shared__ unsigned short As[2][64][72];
    __shared__ unsigned short Bs[64][72];
    const int tid = threadIdx.x;
    const int wave = tid >> 6, lane = tid & 63;
    const int wr = wave >> 1, wc = wave & 1;
    const int quad = lane >> 4, l15 = lane & 15;
    const int m0 = blockIdx.y * 64, n0 = blockIdx.x * 64;
    f32x4 acc[2][2] = {};
    for (int k0 = 0; k0 < KK; k0 += 64) {
        const int seg = k0 / K;
        const int ks = k0 - seg * K;
#pragma unroll
        for (int i = 0; i < 2; i++) {
            int idx = tid + i * 256;
            int r = idx >> 3, cv = (idx & 7) * 8;
            const float* ap = &A[(size_t)(m0 + r) * K + ks + cv];
            const float4 v0 = *(const float4*)ap;
            const float4 v1 = *(const float4*)(ap + 4);
            float va[8] = {v0.x, v0.y, v0.z, v0.w, v1.x, v1.y, v1.z, v1.w};
            short8 h8, l8;
#pragma unroll
            for (int j = 0; j < 8; j++) {
                unsigned short hh = f2bfu(va[j]);
                h8[j] = (short)hh;
                l8[j] = (short)f2bfu(va[j] - bfu2f(hh));
            }
            *(short8*)&As[0][r][cv] = h8;
            *(short8*)&As[1][r][cv] = l8;
            *(short8*)&Bs[r][cv] = *(const short8*)&Bt3[(size_t)(n0 + r) * KK + k0 + cv];
        }
        __syncthreads();
        const int abank = (seg < 2) ? 0 : 1;
#pragma unroll
        for (int kk = 0; kk < 64; kk += 32) {
            short8 a[2], b[2];
#pragma unroll
            for (int t = 0; t < 2; t++) {
                a[t] = *(const short8*)&As[abank][wr * 32 + t * 16 + l15][kk + quad * 8];
                b[t] = *(const short8*)&Bs[wc * 32 + t * 16 + l15][kk + quad * 8];
            }
#pragma unroll
            for (int mt = 0; mt < 2; mt++)
#pragma unroll
                for (int nt = 0; nt < 2; nt++)
                    acc[mt][nt] = __builtin_amdgcn_mfma_f32_16x16x32_bf16(
                        a[mt], b[nt], acc[mt][nt], 0, 0, 0);
        }
        __syncthreads();
    }
#pragma unroll
    for (int mt = 0; mt < 2; mt++)
#pragma unroll
        for (int nt = 0; nt < 2; nt++)
#pragma unroll
            for (int r = 0; r < 4; r++) {
                int row = m0 + wr * 32 + mt * 16 + quad * 4 + r;
                int col = n0 + wc * 32 + nt * 16 + l15;
                C[(size_t)row * N + col] = acc[mt][nt][r];
            }
}

// ---------- GAT aggregate: one WAVE per dst node, all heads; coalesced row gathers ----------
template <int H, bool ELU>
__global__ __launch_bounds__(256)
void gat_agg2(const int* __restrict__ csr, const int* __restrict__ rs,
              const unsigned short* __restrict__ hs,  // [Ns, H*64] bf16
              const float* __restrict__ es,           // [Ns, H]
              const float* __restrict__ ed,           // [Nd, H]
              const float* __restrict__ bias,         // [H*64] or null
              float* __restrict__ out,                // [Nd, H*64] fp32
              int Nd) {
    constexpr int LH = (H == 8) ? 3 : 2;
    constexpr int EPC = 64 >> LH;
    const int lane = threadIdx.x & 63;
    const int d = blockIdx.x * (blockDim.x >> 6) + (threadIdx.x >> 6);
    if (d >= Nd) return;
    const int beg = rs[d];
    const int deg = rs[d + 1] - beg;
    const int n = deg + 1;
    const int h = lane & (H - 1);
    const int e0 = lane >> LH;
    const float edh = ed[(size_t)d * H + h];
    float mx = -1e30f;
    for (int j0 = 0; j0 < n; j0 += EPC) {
        int j = j0 + e0;
        if (j < n) {
            int s = (j < deg) ? csr[beg + j] : d;
            float a = es[(size_t)s * H + h] + edh;
            a = (a > 0.0f) ? a : 0.2f * a;
            mx = fmaxf(mx, a);
        }
    }
#pragma unroll
    for (int off = H; off < 64; off <<= 1) mx = fmaxf(mx, __shfl_xor(mx, off));
    float den = 0.0f;
    for (int j0 = 0; j0 < n; j0 += EPC) {
        int j = j0 + e0;
        if (j < n) {
            int s = (j < deg) ? csr[beg + j] : d;
            float a = es[(size_t)s * H + h] + edh;
            a = (a > 0.0f) ? a : 0.2f * a;
            den += expf(a - mx);
        }
    }
#pragma unroll
    for (int off = H; off < 64; off <<= 1) den += __shfl_xor(den, off);
    const float inv = 1.0f / den;
    const int hB = lane >> (6 - LH);
    const float mB = __shfl(mx, hB);
    const float invB = __shfl(inv, hB);
    const float edhB = __shfl(edh, hB);
    using V = typename VecT<H>::T;
    float acc[H] = {};
    const size_t rowoff = (size_t)lane * H;
    int j = 0;
    for (; j + 4 <= n; j += 4) {
        int s[4]; V rv[4]; float w[4];
#pragma unroll
        for (int u = 0; u < 4; u++) { int jj = j + u; s[u] = (jj < deg) ? csr[beg + jj] : d; }
#pragma unroll
        for (int u = 0; u < 4; u++) rv[u] = *(const V*)&hs[(size_t)s[u] * (H * 64) + rowoff];
#pragma unroll
        for (int u = 0; u < 4; u++) {
            float a = es[(size_t)s[u] * H + hB] + edhB;
            a = (a > 0.0f) ? a : 0.2f * a;
            w[u] = expf(a - mB) * invB;
        }
#pragma unroll
        for (int u = 0; u < 4; u++)
#pragma unroll
            for (int k = 0; k < H; k++) acc[k] += w[u] * bfu2f((unsigned short)rv[u][k]);
    }
    for (; j < n; j++) {
        int s = (j < deg) ? csr[beg + j] : d;
        V rv = *(const V*)&hs[(size_t)s * (H * 64) + rowoff];
        float a = es[(size_t)s * H + hB] + edhB;
        a = (a > 0.0f) ? a : 0.2f * a;
        float w = expf(a - mB) * invB;
#pragma unroll
        for (int k = 0; k < H; k++) acc[k] += w * bfu2f((unsigned short)rv[k]);
    }
#pragma unroll
    for (int k = 0; k < H; k++) {
        float v = acc[k];
        if (ELU) {
            v += bias[lane * H + k];
            v = (v > 0.0f) ? v : expm1f(v);
        }
        acc[k] = v;
    }
    float* op = out + (size_t)d * (H * 64) + rowoff;
#pragma unroll
    for (int q = 0; q < H / 4; q++)
        *(float4*)&op[q * 4] = *(float4*)&acc[q * 4];
}

// ---------- final ----------
__global__ void final_kernel(const float* __restrict__ acc2, const float* __restrict__ bias2,
                             const float* __restrict__ fbuf, const float* __restrict__ flat_b,
                             const float* __restrict__ last, const float* __restrict__ outW,
                             const float* __restrict__ outb, float* __restrict__ out, int N) {
    int n = blockIdx.x * blockDim.x + threadIdx.x;
    if (n >= N) return;
    float s = outb[0];
    const float* a = acc2 + (size_t)n * 256;
    for (int c = 0; c < 64; c++) {
        float h2 = 0.25f * (a[c] + a[64 + c] + a[128 + c] + a[192 + c]) + bias2[c];
        s += h2 * outW[c];
        s += (fbuf[(size_t)n * 64 + c] + flat_b[c]) * outW[64 + c];
        s += last[(size_t)n * 64 + c] * outW[128 + c];
    }
    out[n] = s;
}

extern "C" void kernel_launch(void* const* d_in, const int* in_sizes, int n_in,
                              void* d_out, int out_size, void* d_ws, size_t ws_size,
                              hipStream_t stream) {
    const float* x    = (const float*)d_in[0];
    const float* flat = (const float*)d_in[1];
    const float* last = (const float*)d_in[2];
    const int*  es1i  = (const int*)d_in[3];
    const int*  ed1i  = (const int*)d_in[4];
    const int*  es2i  = (const int*)d_in[5];
    const int*  ed2i  = (const int*)d_in[6];
    const float* W1s  = (const float*)d_in[7];
    const float* W1d  = (const float*)d_in[8];
    const float* a1s  = (const float*)d_in[9];
    const float* a1d  = (const float*)d_in[10];
    const float* b1   = (const float*)d_in[11];
    const float* W2s  = (const float*)d_in[12];
    const float* W2d  = (const float*)d_in[13];
    const float* a2s  = (const float*)d_in[14];
    const float* a2d  = (const float*)d_in[15];
    const float* b2   = (const float*)d_in[16];
    const float* fW   = (const float*)d_in[17];
    const float* fb   = (const float*)d_in[18];
    const float* oW   = (const float*)d_in[19];
    const float* ob   = (const float*)d_in[20];
    float* out = (float*)d_out;

    float* ws = (float*)d_ws;
    // ---- layout (float-element offsets; proven footprint) ----
    unsigned short* hs1_bf = (unsigned short*)ws;                  // 40,960,000 us
    unsigned short* hd1_bf = (unsigned short*)(ws + 20480000);     //  8,192,000 us
    float* es1f = ws + 24576000;                                   // 640,000
    float* ed1f = ws + 25216000;                                   // 128,000
    float* acc1 = ws + 25344000;                                   // 8,192,000 -> 33,536,000
    unsigned short* wb = (unsigned short*)(ws + 54016000);
    unsigned short* w1s_pk = wb;                                   // 131072 us each (spaced 262144)
    unsigned short* w1d_pk = wb + 262144;
    unsigned short* w2s_pk = wb + 524288;
    unsigned short* w2d_pk = wb + 786432;
    unsigned short* fw_t3  = wb + 1048576;
    int* ibase   = (int*)(ws + 54816000);
    int* cnt1    = ibase;
    int* cursor1 = ibase + 16000;
    int* cnt2    = ibase + 32000;
    int* cursor2 = ibase + 36096;
    int* start1  = ibase + 40192;
    int* start2  = ibase + 56193;
    int* csr1    = ibase + 60290;
    int* csr2    = ibase + 316290;
    const size_t NEED = ((size_t)54816000 + 381826) * 4;
    if (ws_size < NEED) {
        fprintf(stderr, "kernel_launch: ws_size %zu < needed %zu\n", ws_size, NEED);
        return;
    }
    unsigned short* hs2_bf = (unsigned short*)ws;
    unsigned short* hd2_bf = (unsigned short*)(ws + 2048000);
    float* es2f = ws + 2572288;
    float* ed2f = ws + 2636288;
    float* acc2 = ws + 2652672;
    float* fbuf = ws + 3701248;

    // ---- prep (1 launch) + CSR build (3 launches) ----
    {
        int total = 262144 + 262144 + 8192 + 40192;
        prep_kernel<<<(total + 255) / 256, 256, 0, stream>>>(
            W1s, W1d, w1s_pk, w1d_pk,
            W2s, W2d, w2s_pk, w2d_pk,
            fW, fw_t3, ibase, 40192);
    }
    hist_dual<<<(E1 + E2 + 255) / 256, 256, 0, stream>>>(ed1i, cnt1, ed2i, cnt2);
    scan_dual<<<2, 1024, 0, stream>>>(cnt1, start1, N2, cnt2, start2, N3);
    fill_dual<<<(E1 + E2 + 255) / 256, 256, 0, stream>>>(
        es1i, ed1i, start1, cursor1, csr1, es2i, ed2i, start2, cursor2, csr2);

    // ---- layer 1: src+dst GEMMs in one grid (streaming fp16, barrier-free) ----
    {
        const int MT = N1 / 64 + N2 / 64;   // 1250 + 250 = 1500 M-panels
        const int NB = 512 / 256;           // 2 column-blocks
        const int grid = 8 * NB * ((MT + 7) / 8);
        gemm_stream<<<grid, 256, 0, stream>>>(
            x, w1s_pk, hs1_bf, a1s, es1f,
            w1d_pk, hd1_bf, a1d, ed1f,
            N1 / 64, MT, NB, 512, 256, 8);
    }
    gat_agg2<8, true><<<N2 / 4, 256, 0, stream>>>(csr1, start1, hs1_bf, es1f, ed1f, b1, acc1, N2);

    // ---- layer 2: src+dst GEMMs in one grid ----
    {
        const int MT = N2 / 64 + N3 / 64;   // 250 + 64 = 314
        const int NB = 1;
        const int grid = 8 * NB * ((MT + 7) / 8);
        gemm_stream<<<grid, 256, 0, stream>>>(
            acc1, w2s_pk, hs2_bf, a2s, es2f,
            w2d_pk, hd2_bf, a2d, ed2f,
            N2 / 64, MT, NB, 256, 512, 4);
    }
    gat_agg2<4, false><<<N3 / 4, 256, 0, stream>>>(csr2, start2, hs2_bf, es2f, ed2f, nullptr, acc2, N3);

    // ---- flat MLP + output ----
    gemm_mfma<<<dim3(1, N3 / 64), 256, 0, stream>>>(flat, fw_t3, fbuf, N3, 64, 128);
    final_kernel<<<(N3 + 255) / 256, 256, 0, stream>>>(acc2, b2, fbuf, fb, last, oW, ob, out, N3);
}

// Round 5
// 381.485 us; speedup vs baseline: 1.2603x; 1.2135x over previous
//
#include <hip/hip_runtime.h>
#include <hip/hip_bf16.h>
#include <cstdio>

typedef __attribute__((ext_vector_type(8))) short short8;
typedef __attribute__((ext_vector_type(4))) short short4v;
typedef __attribute__((ext_vector_type(8))) _Float16 half8;
typedef __attribute__((ext_vector_type(4))) float f32x4;

template <int H> struct VecT;
template <> struct VecT<8> { using T = short8; };
template <> struct VecT<4> { using T = short4v; };

// ---------- bf16/fp16 helpers ----------
__device__ __forceinline__ float bfu2f(unsigned short u) {
    return __uint_as_float(((unsigned)u) << 16);
}
__device__ __forceinline__ unsigned short f2bfu(float f) {   // RNE
    __hip_bfloat16 b = __float2bfloat16(f);
    union { __hip_bfloat16 b; unsigned short u; } cv; cv.b = b;
    return cv.u;
}
__device__ __forceinline__ unsigned short f2hu(float f) {    // fp16 RNE bits
    _Float16 h = (_Float16)f;
    union { _Float16 h; unsigned short u; } cv; cv.h = h;
    return cv.u;
}

// ---------- graph/model dims ----------
#define N1 80000
#define N2 16000
#define N3 4096
#define E1 256000
#define E2 65536

// ---------- fused prep: weight fp16 frag-major pack + flat Bt3 + int zeroing ----------
// Packed layout per matrix: [n16][k32][lane(64)][8] f16 bits, where
// col = n16*16 + (lane&15), k = k32*32 + (lane>>4)*8 + e. A B-fragment load is
// then 64 lanes x contiguous 16B = 1KB fully coalesced, single MFMA operand.
__global__ void prep_kernel(const float* __restrict__ W1s, const float* __restrict__ W1d,
                            unsigned short* __restrict__ w1s_pk, unsigned short* __restrict__ w1d_pk,
                            const float* __restrict__ W2s, const float* __restrict__ W2d,
                            unsigned short* __restrict__ w2s_pk, unsigned short* __restrict__ w2d_pk,
                            const float* __restrict__ fW, unsigned short* __restrict__ fw_t3,
                            int* __restrict__ zbase, int zn) {
    int i = blockIdx.x * blockDim.x + threadIdx.x;
    const int S0 = 262144, S1 = 262144, S2 = 8192;
    if (i < S0) {
        const float* W = (i < 131072) ? W1s : W1d;
        unsigned short* pk = (i < 131072) ? w1s_pk : w1d_pk;
        int j = i & 131071;
        int k = j >> 9, n = j & 511;            // [K=256][N=512] row-major, KS=8
        int n16 = n >> 4, l = n & 15, k32 = k >> 5, qq = (k >> 3) & 3, e = k & 7;
        size_t base = ((size_t)(n16 * 8 + k32)) * 512 + (qq * 16 + l) * 8 + e;
        pk[base] = f2hu(W[j]);
    } else if (i < S0 + S1) {
        int ii = i - S0;
        const float* W = (ii < 131072) ? W2s : W2d;
        unsigned short* pk = (ii < 131072) ? w2s_pk : w2d_pk;
        int j = ii & 131071;
        int k = j >> 8, n = j & 255;            // [K=512][N=256] row-major, KS=16
        int n16 = n >> 4, l = n & 15, k32 = k >> 5, qq = (k >> 3) & 3, e = k & 7;
        size_t base = ((size_t)(n16 * 16 + k32)) * 512 + (qq * 16 + l) * 8 + e;
        pk[base] = f2hu(W[j]);
    } else if (i < S0 + S1 + S2) {
        int j = i - S0 - S1;
        int k = j >> 6, n = j & 63;             // K=128, N=64 (flat MLP, bf16 hi/lo trick)
        float v = fW[j];
        unsigned short h = f2bfu(v);
        unsigned short l = f2bfu(v - bfu2f(h));
        size_t base = (size_t)n * 384;
        fw_t3[base + k] = h;
        fw_t3[base + 128 + k] = l;
        fw_t3[base + 256 + k] = h;
    } else {
        int j = i - S0 - S1 - S2;
        if (j < zn) zbase[j] = 0;
    }
}

// ---------- CSR build (both graphs per launch) ----------
__global__ void hist_dual(const int* __restrict__ d1, int* __restrict__ c1,
                          const int* __restrict__ d2, int* __restrict__ c2) {
    int i = blockIdx.x * blockDim.x + threadIdx.x;
    if (i < E1) {
        int d = d1[i];
        if ((unsigned)d < (unsigned)N2) atomicAdd(&c1[d], 1);
    } else if (i < E1 + E2) {
        int d = d2[i - E1];
        if ((unsigned)d < (unsigned)N3) atomicAdd(&c2[d], 1);
    }
}
__global__ __launch_bounds__(1024)
void scan_dual(const int* __restrict__ c1, int* __restrict__ s1, int Nd1,
               const int* __restrict__ c2, int* __restrict__ s2, int Nd2) {
    const int* cnt = (blockIdx.x == 0) ? c1 : c2;
    int* start = (blockIdx.x == 0) ? s1 : s2;
    int Nd = (blockIdx.x == 0) ? Nd1 : Nd2;
    __shared__ int part[1024];
    int t = threadIdx.x;
    int k = (Nd + 1023) >> 10;
    int lo = t * k, hi = min(lo + k, Nd);
    if (lo > Nd) lo = Nd;
    int s = 0;
    for (int i = lo; i < hi; i++) s += cnt[i];
    part[t] = s;
    __syncthreads();
    for (int off = 1; off < 1024; off <<= 1) {
        int v = (t >= off) ? part[t - off] : 0;
        __syncthreads();
        part[t] += v;
        __syncthreads();
    }
    int run = (t > 0) ? part[t - 1] : 0;
    for (int i = lo; i < hi; i++) { start[i] = run; run += cnt[i]; }
    if (t == 1023) start[Nd] = part[1023];
}
__global__ void fill_dual(const int* __restrict__ sa1, const int* __restrict__ da1,
                          const int* __restrict__ st1, int* __restrict__ cu1, int* __restrict__ cs1,
                          const int* __restrict__ sa2, const int* __restrict__ da2,
                          const int* __restrict__ st2, int* __restrict__ cu2, int* __restrict__ cs2) {
    int i = blockIdx.x * blockDim.x + threadIdx.x;
    const int *sa, *da, *st;
    int *cu, *cs;
    int Nd, Ns, e;
    if (i < E1) { sa = sa1; da = da1; st = st1; cu = cu1; cs = cs1; Nd = N2; Ns = N1; e = i; }
    else if (i < E1 + E2) { sa = sa2; da = da2; st = st2; cu = cu2; cs = cs2; Nd = N3; Ns = N2; e = i - E1; }
    else return;
    int d = da[e];
    if ((unsigned)d >= (unsigned)Nd) return;
    int p = atomicAdd(&cu[d], 1);
    int idx = st[d] + p;
    if (idx >= st[d + 1]) return;
    int s = sa[e];
    if ((unsigned)s >= (unsigned)Ns) s = 0;
    cs[idx] = s;
}

// ---------- fp16 MFMA GEMM, LDS-shared A, safe barriers ----------
// Block = 4 waves, tile 64 rows x 256 cols (wave owns 64x64). A staged once per block
// into double-buffered LDS (pad 40 halfs -> only free 2-way conflicts); each thread
// stages 16B/step (fp32->fp16 cvt in regs for L1, direct fp16 for L2). One
// __syncthreads() per K-step. B from fp16 frag-major pack (L2-resident, 1KB
// coalesced per fragment), reloaded right after last use so its latency hides
// under the remaining MFMAs + barrier.
// Fused escore epilogue: es[row, head] = sum_c C_f32[row, head*64+c]*att[head*64+c].
template <bool AF16>
__global__ __launch_bounds__(256, 2)
void gemm_lds(const void* __restrict__ Ax,
              const unsigned short* __restrict__ Bp1, unsigned short* __restrict__ C1,
              const float* __restrict__ att1, float* __restrict__ es1,
              const unsigned short* __restrict__ Bp2, unsigned short* __restrict__ C2,
              const float* __restrict__ att2, float* __restrict__ es2,
              int Mb1, int MT, int NB, int N, int K, int H) {
    __shared__ alignas(16) _Float16 As[2][64][40];
    // XCD swizzle: hw round-robins blockIdx over 8 XCDs; consecutive per-XCD slots
    // walk M-panels so each panel's column-blocks share one XCD's L2.
    const int hb = blockIdx.x;
    const int xcd = hb & 7;
    const int sI = hb >> 3;
    const int mt = (sI / NB) * 8 + xcd;
    const int nb = sI % NB;
    if (mt >= MT) return;
    const unsigned short* Bp; unsigned short* C; const float* att; float* es_out;
    int m0;
    if (mt < Mb1) { Bp = Bp1; C = C1; att = att1; es_out = es1; m0 = mt * 64; }
    else          { Bp = Bp2; C = C2; att = att2; es_out = es2; m0 = (mt - Mb1) * 64; }
    const int tid = threadIdx.x;
    const int wave = tid >> 6, lane = tid & 63;
    const int q = lane >> 4, l15 = lane & 15;
    const int n0 = nb * 256 + wave * 64;
    const int KS = K >> 5;
    const int arow = tid >> 2, ac8 = (tid & 3) * 8;   // staging: 16B fp16 per thread per step
    const unsigned short* Bbase = Bp + (size_t)(n0 >> 4) * KS * 512 + lane * 8;

    f32x4 acc[4][4] = {};
    half8 b[4];
    float4 s0, s1;   // L1 staging (fp32)
    half8 sh;        // L2 staging (fp16)

    auto stageLoad = [&](int t) {
        if constexpr (AF16) {
            const _Float16* p = (const _Float16*)Ax + (size_t)(m0 + arow) * K + t * 32 + ac8;
            sh = *(const half8*)p;
        } else {
            const float* p = (const float*)Ax + (size_t)(m0 + arow) * K + t * 32 + ac8;
            s0 = *(const float4*)p;
            s1 = *(const float4*)(p + 4);
        }
    };
    auto stageWrite = [&](int buf) {
        half8 v;
        if constexpr (AF16) {
            v = sh;
        } else {
            v[0] = (_Float16)s0.x; v[1] = (_Float16)s0.y;
            v[2] = (_Float16)s0.z; v[3] = (_Float16)s0.w;
            v[4] = (_Float16)s1.x; v[5] = (_Float16)s1.y;
            v[6] = (_Float16)s1.z; v[7] = (_Float16)s1.w;
        }
        *(half8*)&As[buf][arow][ac8] = v;
    };
    auto loadB = [&](int k32, int nt) {
        b[nt] = *(const half8*)(Bbase + ((size_t)nt * KS + k32) * 512);
    };

    // prologue: stage step 0, B0 in flight
    stageLoad(0);
#pragma unroll
    for (int nt = 0; nt < 4; nt++) loadB(0, nt);
    stageWrite(0);
    __syncthreads();

    int cur = 0;
    for (int t = 0; t < KS; t++) {
        const bool hn = (t + 1) < KS;
        if (hn) stageLoad(t + 1);          // global->reg, lands during this step's MFMAs
#pragma unroll
        for (int rg = 0; rg < 4; rg++) {
            half8 a = *(const half8*)&As[cur][rg * 16 + l15][q * 8];
#pragma unroll
            for (int nt = 0; nt < 4; nt++) {
                acc[rg][nt] = __builtin_amdgcn_mfma_f32_16x16x32_f16(a, b[nt], acc[rg][nt], 0, 0, 0);
                if (rg == 3 && hn) loadB(t + 1, nt);   // reload right after last use
            }
        }
        if (hn) {
            stageWrite(cur ^ 1);
            __syncthreads();
        }
        cur ^= 1;
    }

    // epilogue: C store (bf16)
#pragma unroll
    for (int rg = 0; rg < 4; rg++)
#pragma unroll
        for (int nt = 0; nt < 4; nt++)
#pragma unroll
            for (int r = 0; r < 4; r++) {
                int row = m0 + rg * 16 + q * 4 + r;
                int col = n0 + nt * 16 + l15;
                C[(size_t)row * N + col] = f2bfu(acc[rg][nt][r]);
            }
    // fused escore (wave owns exactly one head's 64 cols)
    {
        const int head = n0 >> 6;
        float av[4];
#pragma unroll
        for (int nt = 0; nt < 4; nt++) av[nt] = att[head * 64 + nt * 16 + l15];
#pragma unroll
        for (int rg = 0; rg < 4; rg++)
#pragma unroll
            for (int r = 0; r < 4; r++) {
                float p = acc[rg][0][r] * av[0] + acc[rg][1][r] * av[1]
                        + acc[rg][2][r] * av[2] + acc[rg][3][r] * av[3];
#pragma unroll
                for (int off = 1; off < 16; off <<= 1) p += __shfl_xor(p, off);
                if (l15 == 0)
                    es_out[(size_t)(m0 + rg * 16 + q * 4 + r) * H + head] = p;
            }
    }
}

// ---------- small MFMA GEMM (64x64 tile, Bt3 layout, fp32 A in-kernel split) — flat only ----------
__global__ __launch_bounds__(256)
void gemm_mfma(const float* __restrict__ A, const unsigned short* __restrict__ Bt3,
               float* __restrict__ C, int M, int N, int K) {
    const int KK = 3 * K;
    __shared__ unsigned short As[2][64][72];
    __shared__ unsigned short Bs[64][72];
    const int tid = threadIdx.x;
    const int wave = tid >> 6, lane = tid & 63;
    const int wr = wave >> 1, wc = wave & 1;
    const int quad = lane >> 4, l15 = lane & 15;
    const int m0 = blockIdx.y * 64, n0 = blockIdx.x * 64;
    f32x4 acc[2][2] = {};
    for (int k0 = 0; k0 < KK; k0 += 64) {
        const int seg = k0 / K;
        const int ks = k0 - seg * K;
#pragma unroll
        for (int i = 0; i < 2; i++) {
            int idx = tid + i * 256;
            int r = idx >> 3, cv = (idx & 7) * 8;
            const float* ap = &A[(size_t)(m0 + r) * K + ks + cv];
            const float4 v0 = *(const float4*)ap;
            const float4 v1 = *(const float4*)(ap + 4);
            float va[8] = {v0.x, v0.y, v0.z, v0.w, v1.x, v1.y, v1.z, v1.w};
            short8 h8, l8;
#pragma unroll
            for (int j = 0; j < 8; j++) {
                unsigned short hh = f2bfu(va[j]);
                h8[j] = (short)hh;
                l8[j] = (short)f2bfu(va[j] - bfu2f(hh));
            }
            *(short8*)&As[0][r][cv] = h8;
            *(short8*)&As[1][r][cv] = l8;
            *(short8*)&Bs[r][cv] = *(const short8*)&Bt3[(size_t)(n0 + r) * KK + k0 + cv];
        }
        __syncthreads();
        const int abank = (seg < 2) ? 0 : 1;
#pragma unroll
        for (int kk = 0; kk < 64; kk += 32) {
            short8 a[2], b[2];
#pragma unroll
            for (int t = 0; t < 2; t++) {
                a[t] = *(const short8*)&As[abank][wr * 32 + t * 16 + l15][kk + quad * 8];
                b[t] = *(const short8*)&Bs[wc * 32 + t * 16 + l15][kk + quad * 8];
            }
#pragma unroll
            for (int mt = 0; mt < 2; mt++)
#pragma unroll
                for (int nt = 0; nt < 2; nt++)
                    acc[mt][nt] = __builtin_amdgcn_mfma_f32_16x16x32_bf16(
                        a[mt], b[nt], acc[mt][nt], 0, 0, 0);
        }
        __syncthreads();
    }
#pragma unroll
    for (int mt = 0; mt < 2; mt++)
#pragma unroll
        for (int nt = 0; nt < 2; nt++)
#pragma unroll
            for (int r = 0; r < 4; r++) {
                int row = m0 + wr * 32 + mt * 16 + quad * 4 + r;
                int col = n0 + wc * 32 + nt * 16 + l15;
                C[(size_t)row * N + col] = acc[mt][nt][r];
            }
}

// ---------- GAT aggregate: one WAVE per dst node, all heads; coalesced row gathers ----------
// HOUT: write fp16 output rows (for feeding the next GEMM's A directly).
template <int H, bool ELU, bool HOUT>
__global__ __launch_bounds__(256)
void gat_agg2(const int* __restrict__ csr, const int* __restrict__ rs,
              const unsigned short* __restrict__ hs,  // [Ns, H*64] bf16
              const float* __restrict__ es,           // [Ns, H]
              const float* __restrict__ ed,           // [Nd, H]
              const float* __restrict__ bias,         // [H*64] or null
              void* __restrict__ out,                 // [Nd, H*64] fp32 or fp16
              int Nd) {
    constexpr int LH = (H == 8) ? 3 : 2;
    constexpr int EPC = 64 >> LH;
    const int lane = threadIdx.x & 63;
    const int d = blockIdx.x * (blockDim.x >> 6) + (threadIdx.x >> 6);
    if (d >= Nd) return;
    const int beg = rs[d];
    const int deg = rs[d + 1] - beg;
    const int n = deg + 1;
    const int h = lane & (H - 1);
    const int e0 = lane >> LH;
    const float edh = ed[(size_t)d * H + h];
    float mx = -1e30f;
    for (int j0 = 0; j0 < n; j0 += EPC) {
        int j = j0 + e0;
        if (j < n) {
            int s = (j < deg) ? csr[beg + j] : d;
            float a = es[(size_t)s * H + h] + edh;
            a = (a > 0.0f) ? a : 0.2f * a;
            mx = fmaxf(mx, a);
        }
    }
#pragma unroll
    for (int off = H; off < 64; off <<= 1) mx = fmaxf(mx, __shfl_xor(mx, off));
    float den = 0.0f;
    for (int j0 = 0; j0 < n; j0 += EPC) {
        int j = j0 + e0;
        if (j < n) {
            int s = (j < deg) ? csr[beg + j] : d;
            float a = es[(size_t)s * H + h] + edh;
            a = (a > 0.0f) ? a : 0.2f * a;
            den += expf(a - mx);
        }
    }
#pragma unroll
    for (int off = H; off < 64; off <<= 1) den += __shfl_xor(den, off);
    const float inv = 1.0f / den;
    const int hB = lane >> (6 - LH);
    const float mB = __shfl(mx, hB);
    const float invB = __shfl(inv, hB);
    const float edhB = __shfl(edh, hB);
    using V = typename VecT<H>::T;
    float acc[H] = {};
    const size_t rowoff = (size_t)lane * H;
    int j = 0;
    for (; j + 4 <= n; j += 4) {
        int s[4]; V rv[4]; float w[4];
#pragma unroll
        for (int u = 0; u < 4; u++) { int jj = j + u; s[u] = (jj < deg) ? csr[beg + jj] : d; }
#pragma unroll
        for (int u = 0; u < 4; u++) rv[u] = *(const V*)&hs[(size_t)s[u] * (H * 64) + rowoff];
#pragma unroll
        for (int u = 0; u < 4; u++) {
            float a = es[(size_t)s[u] * H + hB] + edhB;
            a = (a > 0.0f) ? a : 0.2f * a;
            w[u] = expf(a - mB) * invB;
        }
#pragma unroll
        for (int u = 0; u < 4; u++)
#pragma unroll
            for (int k = 0; k < H; k++) acc[k] += w[u] * bfu2f((unsigned short)rv[u][k]);
    }
    for (; j < n; j++) {
        int s = (j < deg) ? csr[beg + j] : d;
        V rv = *(const V*)&hs[(size_t)s * (H * 64) + rowoff];
        float a = es[(size_t)s * H + hB] + edhB;
        a = (a > 0.0f) ? a : 0.2f * a;
        float w = expf(a - mB) * invB;
#pragma unroll
        for (int k = 0; k < H; k++) acc[k] += w * bfu2f((unsigned short)rv[k]);
    }
#pragma unroll
    for (int k = 0; k < H; k++) {
        float v = acc[k];
        if (ELU) {
            v += bias[lane * H + k];
            v = (v > 0.0f) ? v : expm1f(v);
        }
        acc[k] = v;
    }
    if constexpr (HOUT) {
        half8 hv;
#pragma unroll
        for (int k = 0; k < H; k++) hv[k] = (_Float16)acc[k];
        _Float16* op = (_Float16*)out + (size_t)d * (H * 64) + rowoff;
        *(half8*)op = hv;    // H==8 only
    } else {
        float* op = (float*)out + (size_t)d * (H * 64) + rowoff;
#pragma unroll
        for (int qd = 0; qd < H / 4; qd++)
            *(float4*)&op[qd * 4] = *(float4*)&acc[qd * 4];
    }
}

// ---------- final ----------
__global__ void final_kernel(const float* __restrict__ acc2, const float* __restrict__ bias2,
                             const float* __restrict__ fbuf, const float* __restrict__ flat_b,
                             const float* __restrict__ last, const float* __restrict__ outW,
                             const float* __restrict__ outb, float* __restrict__ out, int N) {
    int n = blockIdx.x * blockDim.x + threadIdx.x;
    if (n >= N) return;
    float s = outb[0];
    const float* a = acc2 + (size_t)n * 256;
    for (int c = 0; c < 64; c++) {
        float h2 = 0.25f * (a[c] + a[64 + c] + a[128 + c] + a[192 + c]) + bias2[c];
        s += h2 * outW[c];
        s += (fbuf[(size_t)n * 64 + c] + flat_b[c]) * outW[64 + c];
        s += last[(size_t)n * 64 + c] * outW[128 + c];
    }
    out[n] = s;
}

extern "C" void kernel_launch(void* const* d_in, const int* in_sizes, int n_in,
                              void* d_out, int out_size, void* d_ws, size_t ws_size,
                              hipStream_t stream) {
    const float* x    = (const float*)d_in[0];
    const float* flat = (const float*)d_in[1];
    const float* last = (const float*)d_in[2];
    const int*  es1i  = (const int*)d_in[3];
    const int*  ed1i  = (const int*)d_in[4];
    const int*  es2i  = (const int*)d_in[5];
    const int*  ed2i  = (const int*)d_in[6];
    const float* W1s  = (const float*)d_in[7];
    const float* W1d  = (const float*)d_in[8];
    const float* a1s  = (const float*)d_in[9];
    const float* a1d  = (const float*)d_in[10];
    const float* b1   = (const float*)d_in[11];
    const float* W2s  = (const float*)d_in[12];
    const float* W2d  = (const float*)d_in[13];
    const float* a2s  = (const float*)d_in[14];
    const float* a2d  = (const float*)d_in[15];
    const float* b2   = (const float*)d_in[16];
    const float* fW   = (const float*)d_in[17];
    const float* fb   = (const float*)d_in[18];
    const float* oW   = (const float*)d_in[19];
    const float* ob   = (const float*)d_in[20];
    float* out = (float*)d_out;

    float* ws = (float*)d_ws;
    // ---- layout (float-element offsets; proven footprint) ----
    unsigned short* hs1_bf = (unsigned short*)ws;                  // 40,960,000 us
    unsigned short* hd1_bf = (unsigned short*)(ws + 20480000);     //  8,192,000 us
    float* es1f = ws + 24576000;                                   // 640,000
    float* ed1f = ws + 25216000;                                   // 128,000
    float* acc1 = ws + 25344000;                                   // L1 out, fp16 [16000*512]
    unsigned short* wb = (unsigned short*)(ws + 54016000);
    unsigned short* w1s_pk = wb;                                   // 131072 us each (spaced 262144)
    unsigned short* w1d_pk = wb + 262144;
    unsigned short* w2s_pk = wb + 524288;
    unsigned short* w2d_pk = wb + 786432;
    unsigned short* fw_t3  = wb + 1048576;
    int* ibase   = (int*)(ws + 54816000);
    int* cnt1    = ibase;
    int* cursor1 = ibase + 16000;
    int* cnt2    = ibase + 32000;
    int* cursor2 = ibase + 36096;
    int* start1  = ibase + 40192;
    int* start2  = ibase + 56193;
    int* csr1    = ibase + 60290;
    int* csr2    = ibase + 316290;
    const size_t NEED = ((size_t)54816000 + 381826) * 4;
    if (ws_size < NEED) {
        fprintf(stderr, "kernel_launch: ws_size %zu < needed %zu\n", ws_size, NEED);
        return;
    }
    unsigned short* hs2_bf = (unsigned short*)ws;
    unsigned short* hd2_bf = (unsigned short*)(ws + 2048000);
    float* es2f = ws + 2572288;
    float* ed2f = ws + 2636288;
    float* acc2 = ws + 2652672;
    float* fbuf = ws + 3701248;
    unsigned short* acc1h = (unsigned short*)acc1;   // fp16 L1 output / L2 A

    // ---- prep (1 launch) + CSR build (3 launches) ----
    {
        int total = 262144 + 262144 + 8192 + 40192;
        prep_kernel<<<(total + 255) / 256, 256, 0, stream>>>(
            W1s, W1d, w1s_pk, w1d_pk,
            W2s, W2d, w2s_pk, w2d_pk,
            fW, fw_t3, ibase, 40192);
    }
    hist_dual<<<(E1 + E2 + 255) / 256, 256, 0, stream>>>(ed1i, cnt1, ed2i, cnt2);
    scan_dual<<<2, 1024, 0, stream>>>(cnt1, start1, N2, cnt2, start2, N3);
    fill_dual<<<(E1 + E2 + 255) / 256, 256, 0, stream>>>(
        es1i, ed1i, start1, cursor1, csr1, es2i, ed2i, start2, cursor2, csr2);

    // ---- layer 1: src+dst GEMMs in one grid (LDS-shared fp16 A) ----
    {
        const int MT = N1 / 64 + N2 / 64;   // 1250 + 250 = 1500 M-panels
        const int NB = 512 / 256;           // 2 column-blocks
        const int grid = 8 * NB * ((MT + 7) / 8);
        gemm_lds<false><<<grid, 256, 0, stream>>>(
            x, w1s_pk, hs1_bf, a1s, es1f,
            w1d_pk, hd1_bf, a1d, ed1f,
            N1 / 64, MT, NB, 512, 256, 8);
    }
    gat_agg2<8, true, true><<<N2 / 4, 256, 0, stream>>>(
        csr1, start1, hs1_bf, es1f, ed1f, b1, acc1h, N2);

    // ---- layer 2: src+dst GEMMs in one grid (A = fp16 from agg1) ----
    {
        const int MT = N2 / 64 + N3 / 64;   // 250 + 64 = 314
        const int NB = 1;
        const int grid = 8 * NB * ((MT + 7) / 8);
        gemm_lds<true><<<grid, 256, 0, stream>>>(
            acc1h, w2s_pk, hs2_bf, a2s, es2f,
            w2d_pk, hd2_bf, a2d, ed2f,
            N2 / 64, MT, NB, 256, 512, 4);
    }
    gat_agg2<4, false, false><<<N3 / 4, 256, 0, stream>>>(
        csr2, start2, hs2_bf, es2f, ed2f, nullptr, acc2, N3);

    // ---- flat MLP + output ----
    gemm_mfma<<<dim3(1, N3 / 64), 256, 0, stream>>>(flat, fw_t3, fbuf, N3, 64, 128);
    final_kernel<<<(N3 + 255) / 256, 256, 0, stream>>>(acc2, b2, fbuf, fb, last, oW, ob, out, N3);
}

// Round 6
// 379.183 us; speedup vs baseline: 1.2680x; 1.0061x over previous
//
#include <hip/hip_runtime.h>
#include <hip/hip_bf16.h>
#include <cstdio>

typedef __attribute__((ext_vector_type(8))) short short8;
typedef __attribute__((ext_vector_type(4))) short short4v;
typedef __attribute__((ext_vector_type(8))) _Float16 half8;
typedef __attribute__((ext_vector_type(4))) float f32x4;

template <int H> struct VecT;
template <> struct VecT<8> { using T = short8; };
template <> struct VecT<4> { using T = short4v; };

// ---------- bf16/fp16 helpers ----------
__device__ __forceinline__ float bfu2f(unsigned short u) {
    return __uint_as_float(((unsigned)u) << 16);
}
__device__ __forceinline__ unsigned short f2bfu(float f) {   // RNE
    __hip_bfloat16 b = __float2bfloat16(f);
    union { __hip_bfloat16 b; unsigned short u; } cv; cv.b = b;
    return cv.u;
}
__device__ __forceinline__ unsigned short f2hu(float f) {    // fp16 RNE bits
    _Float16 h = (_Float16)f;
    union { _Float16 h; unsigned short u; } cv; cv.h = h;
    return cv.u;
}

// ---------- graph/model dims ----------
#define N1 80000
#define N2 16000
#define N3 4096
#define E1 256000
#define E2 65536

// ---------- fused prep: weight fp16 frag-major pack + flat Bt3 + int zeroing ----------
// Packed layout per matrix: [n16][k32][lane(64)][8] f16 bits, where
// col = n16*16 + (lane&15), k = k32*32 + (lane>>4)*8 + e. A B-fragment load is
// then 64 lanes x contiguous 16B = 1KB fully coalesced, single MFMA operand.
__global__ void prep_kernel(const float* __restrict__ W1s, const float* __restrict__ W1d,
                            unsigned short* __restrict__ w1s_pk, unsigned short* __restrict__ w1d_pk,
                            const float* __restrict__ W2s, const float* __restrict__ W2d,
                            unsigned short* __restrict__ w2s_pk, unsigned short* __restrict__ w2d_pk,
                            const float* __restrict__ fW, unsigned short* __restrict__ fw_t3,
                            int* __restrict__ zbase, int zn) {
    int i = blockIdx.x * blockDim.x + threadIdx.x;
    const int S0 = 262144, S1 = 262144, S2 = 8192;
    if (i < S0) {
        const float* W = (i < 131072) ? W1s : W1d;
        unsigned short* pk = (i < 131072) ? w1s_pk : w1d_pk;
        int j = i & 131071;
        int k = j >> 9, n = j & 511;            // [K=256][N=512] row-major, KS=8
        int n16 = n >> 4, l = n & 15, k32 = k >> 5, qq = (k >> 3) & 3, e = k & 7;
        size_t base = ((size_t)(n16 * 8 + k32)) * 512 + (qq * 16 + l) * 8 + e;
        pk[base] = f2hu(W[j]);
    } else if (i < S0 + S1) {
        int ii = i - S0;
        const float* W = (ii < 131072) ? W2s : W2d;
        unsigned short* pk = (ii < 131072) ? w2s_pk : w2d_pk;
        int j = ii & 131071;
        int k = j >> 8, n = j & 255;            // [K=512][N=256] row-major, KS=16
        int n16 = n >> 4, l = n & 15, k32 = k >> 5, qq = (k >> 3) & 3, e = k & 7;
        size_t base = ((size_t)(n16 * 16 + k32)) * 512 + (qq * 16 + l) * 8 + e;
        pk[base] = f2hu(W[j]);
    } else if (i < S0 + S1 + S2) {
        int j = i - S0 - S1;
        int k = j >> 6, n = j & 63;             // K=128, N=64 (flat MLP, bf16 hi/lo trick)
        float v = fW[j];
        unsigned short h = f2bfu(v);
        unsigned short l = f2bfu(v - bfu2f(h));
        size_t base = (size_t)n * 384;
        fw_t3[base + k] = h;
        fw_t3[base + 128 + k] = l;
        fw_t3[base + 256 + k] = h;
    } else {
        int j = i - S0 - S1 - S2;
        if (j < zn) zbase[j] = 0;
    }
}

// ---------- CSR build (both graphs per launch) ----------
__global__ void hist_dual(const int* __restrict__ d1, int* __restrict__ c1,
                          const int* __restrict__ d2, int* __restrict__ c2) {
    int i = blockIdx.x * blockDim.x + threadIdx.x;
    if (i < E1) {
        int d = d1[i];
        if ((unsigned)d < (unsigned)N2) atomicAdd(&c1[d], 1);
    } else if (i < E1 + E2) {
        int d = d2[i - E1];
        if ((unsigned)d < (unsigned)N3) atomicAdd(&c2[d], 1);
    }
}
__global__ __launch_bounds__(1024)
void scan_dual(const int* __restrict__ c1, int* __restrict__ s1, int Nd1,
               const int* __restrict__ c2, int* __restrict__ s2, int Nd2) {
    const int* cnt = (blockIdx.x == 0) ? c1 : c2;
    int* start = (blockIdx.x == 0) ? s1 : s2;
    int Nd = (blockIdx.x == 0) ? Nd1 : Nd2;
    __shared__ int part[1024];
    int t = threadIdx.x;
    int k = (Nd + 1023) >> 10;
    int lo = t * k, hi = min(lo + k, Nd);
    if (lo > Nd) lo = Nd;
    int s = 0;
    for (int i = lo; i < hi; i++) s += cnt[i];
    part[t] = s;
    __syncthreads();
    for (int off = 1; off < 1024; off <<= 1) {
        int v = (t >= off) ? part[t - off] : 0;
        __syncthreads();
        part[t] += v;
        __syncthreads();
    }
    int run = (t > 0) ? part[t - 1] : 0;
    for (int i = lo; i < hi; i++) { start[i] = run; run += cnt[i]; }
    if (t == 1023) start[Nd] = part[1023];
}
__global__ void fill_dual(const int* __restrict__ sa1, const int* __restrict__ da1,
                          const int* __restrict__ st1, int* __restrict__ cu1, int* __restrict__ cs1,
                          const int* __restrict__ sa2, const int* __restrict__ da2,
                          const int* __restrict__ st2, int* __restrict__ cu2, int* __restrict__ cs2) {
    int i = blockIdx.x * blockDim.x + threadIdx.x;
    const int *sa, *da, *st;
    int *cu, *cs;
    int Nd, Ns, e;
    if (i < E1) { sa = sa1; da = da1; st = st1; cu = cu1; cs = cs1; Nd = N2; Ns = N1; e = i; }
    else if (i < E1 + E2) { sa = sa2; da = da2; st = st2; cu = cu2; cs = cs2; Nd = N3; Ns = N2; e = i - E1; }
    else return;
    int d = da[e];
    if ((unsigned)d >= (unsigned)Nd) return;
    int p = atomicAdd(&cu[d], 1);
    int idx = st[d] + p;
    if (idx >= st[d + 1]) return;
    int s = sa[e];
    if ((unsigned)s >= (unsigned)Ns) s = 0;
    cs[idx] = s;
}

// ---------- fp16 MFMA GEMM, LDS-shared A, K-step 64 ----------
// Block = 4 waves, tile 64 rows x 256 cols (wave owns 64x64). A staged once per block
// into double-buffered LDS (row pad to 72 halfs); each thread stages 32B/step.
// One __syncthreads() per 64-wide K-step (32 MFMAs between barriers). B from fp16
// frag-major pack (L2-resident, 1KB coalesced per fragment), b[kh][nt] reloaded for
// step t+1 right after its last use in step t so its latency hides under the
// remaining MFMAs + barrier.
// Fused escore epilogue: es[row, head] = sum_c C_f32[row, head*64+c]*att[head*64+c].
template <bool AF16>
__global__ __launch_bounds__(256, 2)
void gemm_lds(const void* __restrict__ Ax,
              const unsigned short* __restrict__ Bp1, unsigned short* __restrict__ C1,
              const float* __restrict__ att1, float* __restrict__ es1,
              const unsigned short* __restrict__ Bp2, unsigned short* __restrict__ C2,
              const float* __restrict__ att2, float* __restrict__ es2,
              int Mb1, int MT, int NB, int N, int K, int H) {
    __shared__ alignas(16) _Float16 As[2][64][72];
    // XCD swizzle: hw round-robins blockIdx over 8 XCDs; consecutive per-XCD slots
    // walk M-panels so each panel's column-blocks share one XCD's L2.
    const int hb = blockIdx.x;
    const int xcd = hb & 7;
    const int sI = hb >> 3;
    const int mt = (sI / NB) * 8 + xcd;
    const int nb = sI % NB;
    if (mt >= MT) return;
    const unsigned short* Bp; unsigned short* C; const float* att; float* es_out;
    int m0;
    if (mt < Mb1) { Bp = Bp1; C = C1; att = att1; es_out = es1; m0 = mt * 64; }
    else          { Bp = Bp2; C = C2; att = att2; es_out = es2; m0 = (mt - Mb1) * 64; }
    const int tid = threadIdx.x;
    const int wave = tid >> 6, lane = tid & 63;
    const int q = lane >> 4, l15 = lane & 15;
    const int n0 = nb * 256 + wave * 64;
    const int KS = K >> 6;                 // 64-wide K-steps
    const int KSB = K >> 5;                // pack's 32-wide k32 count
    const int arow = tid >> 2, ac16 = (tid & 3) * 16;   // staging: 32B fp16/thread/step
    const unsigned short* Bbase = Bp + (size_t)(n0 >> 4) * KSB * 512 + lane * 8;

    f32x4 acc[4][4] = {};
    half8 b[2][4];
    float4 s0, s1, s2, s3;   // L1 staging (16 fp32)
    half8 sh0, sh1;          // L2 staging (16 fp16)

    auto stageLoad = [&](int t) {
        if constexpr (AF16) {
            const _Float16* p = (const _Float16*)Ax + (size_t)(m0 + arow) * K + t * 64 + ac16;
            sh0 = *(const half8*)p;
            sh1 = *(const half8*)(p + 8);
        } else {
            const float* p = (const float*)Ax + (size_t)(m0 + arow) * K + t * 64 + ac16;
            s0 = *(const float4*)p;
            s1 = *(const float4*)(p + 4);
            s2 = *(const float4*)(p + 8);
            s3 = *(const float4*)(p + 12);
        }
    };
    auto stageWrite = [&](int buf) {
        half8 v0, v1;
        if constexpr (AF16) {
            v0 = sh0; v1 = sh1;
        } else {
            v0[0] = (_Float16)s0.x; v0[1] = (_Float16)s0.y;
            v0[2] = (_Float16)s0.z; v0[3] = (_Float16)s0.w;
            v0[4] = (_Float16)s1.x; v0[5] = (_Float16)s1.y;
            v0[6] = (_Float16)s1.z; v0[7] = (_Float16)s1.w;
            v1[0] = (_Float16)s2.x; v1[1] = (_Float16)s2.y;
            v1[2] = (_Float16)s2.z; v1[3] = (_Float16)s2.w;
            v1[4] = (_Float16)s3.x; v1[5] = (_Float16)s3.y;
            v1[6] = (_Float16)s3.z; v1[7] = (_Float16)s3.w;
        }
        *(half8*)&As[buf][arow][ac16] = v0;
        *(half8*)&As[buf][arow][ac16 + 8] = v1;
    };
    auto loadB = [&](int k32, int kh, int nt) {
        b[kh][nt] = *(const half8*)(Bbase + ((size_t)nt * KSB + k32) * 512);
    };

    // prologue: stage step 0, both k-halves of B0 in flight
    stageLoad(0);
#pragma unroll
    for (int kh = 0; kh < 2; kh++)
#pragma unroll
        for (int nt = 0; nt < 4; nt++) loadB(kh, kh, nt);
    stageWrite(0);
    __syncthreads();

    int cur = 0;
    for (int t = 0; t < KS; t++) {
        const bool hn = (t + 1) < KS;
        if (hn) stageLoad(t + 1);          // global->reg, lands during this step's 32 MFMAs
#pragma unroll
        for (int kh = 0; kh < 2; kh++) {
#pragma unroll
            for (int rg = 0; rg < 4; rg++) {
                half8 a = *(const half8*)&As[cur][rg * 16 + l15][kh * 32 + q * 8];
#pragma unroll
                for (int nt = 0; nt < 4; nt++) {
                    acc[rg][nt] = __builtin_amdgcn_mfma_f32_16x16x32_f16(a, b[kh][nt], acc[rg][nt], 0, 0, 0);
                    if (rg == 3 && hn) loadB(2 * (t + 1) + kh, kh, nt);  // reload after last use
                }
            }
        }
        if (hn) {
            stageWrite(cur ^ 1);
            __syncthreads();
        }
        cur ^= 1;
    }

    // epilogue: C store (bf16)
#pragma unroll
    for (int rg = 0; rg < 4; rg++)
#pragma unroll
        for (int nt = 0; nt < 4; nt++)
#pragma unroll
            for (int r = 0; r < 4; r++) {
                int row = m0 + rg * 16 + q * 4 + r;
                int col = n0 + nt * 16 + l15;
                C[(size_t)row * N + col] = f2bfu(acc[rg][nt][r]);
            }
    // fused escore (wave owns exactly one head's 64 cols)
    {
        const int head = n0 >> 6;
        float av[4];
#pragma unroll
        for (int nt = 0; nt < 4; nt++) av[nt] = att[head * 64 + nt * 16 + l15];
#pragma unroll
        for (int rg = 0; rg < 4; rg++)
#pragma unroll
            for (int r = 0; r < 4; r++) {
                float p = acc[rg][0][r] * av[0] + acc[rg][1][r] * av[1]
                        + acc[rg][2][r] * av[2] + acc[rg][3][r] * av[3];
#pragma unroll
                for (int off = 1; off < 16; off <<= 1) p += __shfl_xor(p, off);
                if (l15 == 0)
                    es_out[(size_t)(m0 + rg * 16 + q * 4 + r) * H + head] = p;
            }
    }
}

// ---------- small MFMA GEMM (64x64 tile, Bt3 layout, fp32 A in-kernel split) — flat only ----------
__global__ __launch_bounds__(256)
void gemm_mfma(const float* __restrict__ A, const unsigned short* __restrict__ Bt3,
               float* __restrict__ C, int M, int N, int K) {
    const int KK = 3 * K;
    __shared__ unsigned short As[2][64][72];
    __shared__ unsigned short Bs[64][72];
    const int tid = threadIdx.x;
    const int wave = tid >> 6, lane = tid & 63;
    const int wr = wave >> 1, wc = wave & 1;
    const int quad = lane >> 4, l15 = lane & 15;
    const int m0 = blockIdx.y * 64, n0 = blockIdx.x * 64;
    f32x4 acc[2][2] = {};
    for (int k0 = 0; k0 < KK; k0 += 64) {
        const int seg = k0 / K;
        const int ks = k0 - seg * K;
#pragma unroll
        for (int i = 0; i < 2; i++) {
            int idx = tid + i * 256;
            int r = idx >> 3, cv = (idx & 7) * 8;
            const float* ap = &A[(size_t)(m0 + r) * K + ks + cv];
            const float4 v0 = *(const float4*)ap;
            const float4 v1 = *(const float4*)(ap + 4);
            float va[8] = {v0.x, v0.y, v0.z, v0.w, v1.x, v1.y, v1.z, v1.w};
            short8 h8, l8;
#pragma unroll
            for (int j = 0; j < 8; j++) {
                unsigned short hh = f2bfu(va[j]);
                h8[j] = (short)hh;
                l8[j] = (short)f2bfu(va[j] - bfu2f(hh));
            }
            *(short8*)&As[0][r][cv] = h8;
            *(short8*)&As[1][r][cv] = l8;
            *(short8*)&Bs[r][cv] = *(const short8*)&Bt3[(size_t)(n0 + r) * KK + k0 + cv];
        }
        __syncthreads();
        const int abank = (seg < 2) ? 0 : 1;
#pragma unroll
        for (int kk = 0; kk < 64; kk += 32) {
            short8 a[2], b[2];
#pragma unroll
            for (int t = 0; t < 2; t++) {
                a[t] = *(const short8*)&As[abank][wr * 32 + t * 16 + l15][kk + quad * 8];
                b[t] = *(const short8*)&Bs[wc * 32 + t * 16 + l15][kk + quad * 8];
            }
#pragma unroll
            for (int mt = 0; mt < 2; mt++)
#pragma unroll
                for (int nt = 0; nt < 2; nt++)
                    acc[mt][nt] = __builtin_amdgcn_mfma_f32_16x16x32_bf16(
                        a[mt], b[nt], acc[mt][nt], 0, 0, 0);
        }
        __syncthreads();
    }
#pragma unroll
    for (int mt = 0; mt < 2; mt++)
#pragma unroll
        for (int nt = 0; nt < 2; nt++)
#pragma unroll
            for (int r = 0; r < 4; r++) {
                int row = m0 + wr * 32 + mt * 16 + quad * 4 + r;
                int col = n0 + wc * 32 + nt * 16 + l15;
                C[(size_t)row * N + col] = acc[mt][nt][r];
            }
}

// ---------- GAT aggregate: one WAVE per dst node, all heads; coalesced row gathers ----------
// Fused max+den pass via register alpha cache (covers <=8 chunks; fallback two-pass).
// 8-deep row-gather pipeline. HOUT: write fp16 output rows (feeds next GEMM's A).
template <int H, bool ELU, bool HOUT>
__global__ __launch_bounds__(256)
void gat_agg2(const int* __restrict__ csr, const int* __restrict__ rs,
              const unsigned short* __restrict__ hs,  // [Ns, H*64] bf16
              const float* __restrict__ es,           // [Ns, H]
              const float* __restrict__ ed,           // [Nd, H]
              const float* __restrict__ bias,         // [H*64] or null
              void* __restrict__ out,                 // [Nd, H*64] fp32 or fp16
              int Nd) {
    constexpr int LH = (H == 8) ? 3 : 2;
    constexpr int EPC = 64 >> LH;
    const int lane = threadIdx.x & 63;
    const int d = blockIdx.x * (blockDim.x >> 6) + (threadIdx.x >> 6);
    if (d >= Nd) return;
    const int beg = rs[d];
    const int deg = rs[d + 1] - beg;
    const int n = deg + 1;
    const int h = lane & (H - 1);
    const int e0 = lane >> LH;
    const float edh = ed[(size_t)d * H + h];
    const int nch = (n + EPC - 1) / EPC;
    float mx = -1e30f;
    float den = 0.0f;
    if (nch <= 8) {
        // fused: one gather pass caches alpha in regs; den from cache
        float ac[8];
#pragma unroll
        for (int c = 0; c < 8; c++) {
            float a = -1e30f;
            if (c < nch) {
                int j = c * EPC + e0;
                if (j < n) {
                    int s = (j < deg) ? csr[beg + j] : d;
                    a = es[(size_t)s * H + h] + edh;
                    a = (a > 0.0f) ? a : 0.2f * a;
                }
            }
            ac[c] = a;
            mx = fmaxf(mx, a);
        }
#pragma unroll
        for (int off = H; off < 64; off <<= 1) mx = fmaxf(mx, __shfl_xor(mx, off));
#pragma unroll
        for (int c = 0; c < 8; c++)
            if (c < nch) den += expf(ac[c] - mx);   // masked lanes underflow to 0
#pragma unroll
        for (int off = H; off < 64; off <<= 1) den += __shfl_xor(den, off);
    } else {
        for (int j0 = 0; j0 < n; j0 += EPC) {
            int j = j0 + e0;
            if (j < n) {
                int s = (j < deg) ? csr[beg + j] : d;
                float a = es[(size_t)s * H + h] + edh;
                a = (a > 0.0f) ? a : 0.2f * a;
                mx = fmaxf(mx, a);
            }
        }
#pragma unroll
        for (int off = H; off < 64; off <<= 1) mx = fmaxf(mx, __shfl_xor(mx, off));
        for (int j0 = 0; j0 < n; j0 += EPC) {
            int j = j0 + e0;
            if (j < n) {
                int s = (j < deg) ? csr[beg + j] : d;
                float a = es[(size_t)s * H + h] + edh;
                a = (a > 0.0f) ? a : 0.2f * a;
                den += expf(a - mx);
            }
        }
#pragma unroll
        for (int off = H; off < 64; off <<= 1) den += __shfl_xor(den, off);
    }
    const float inv = 1.0f / den;
    const int hB = lane >> (6 - LH);
    const float mB = __shfl(mx, hB);
    const float invB = __shfl(inv, hB);
    const float edhB = __shfl(edh, hB);
    using V = typename VecT<H>::T;
    float acc[H] = {};
    const size_t rowoff = (size_t)lane * H;
    int j = 0;
    for (; j + 8 <= n; j += 8) {
        int s[8]; V rv[8]; float w[8];
#pragma unroll
        for (int u = 0; u < 8; u++) { int jj = j + u; s[u] = (jj < deg) ? csr[beg + jj] : d; }
#pragma unroll
        for (int u = 0; u < 8; u++) rv[u] = *(const V*)&hs[(size_t)s[u] * (H * 64) + rowoff];
#pragma unroll
        for (int u = 0; u < 8; u++) {
            float a = es[(size_t)s[u] * H + hB] + edhB;
            a = (a > 0.0f) ? a : 0.2f * a;
            w[u] = expf(a - mB) * invB;
        }
#pragma unroll
        for (int u = 0; u < 8; u++)
#pragma unroll
            for (int k = 0; k < H; k++) acc[k] += w[u] * bfu2f((unsigned short)rv[u][k]);
    }
    for (; j + 4 <= n; j += 4) {
        int s[4]; V rv[4]; float w[4];
#pragma unroll
        for (int u = 0; u < 4; u++) { int jj = j + u; s[u] = (jj < deg) ? csr[beg + jj] : d; }
#pragma unroll
        for (int u = 0; u < 4; u++) rv[u] = *(const V*)&hs[(size_t)s[u] * (H * 64) + rowoff];
#pragma unroll
        for (int u = 0; u < 4; u++) {
            float a = es[(size_t)s[u] * H + hB] + edhB;
            a = (a > 0.0f) ? a : 0.2f * a;
            w[u] = expf(a - mB) * invB;
        }
#pragma unroll
        for (int u = 0; u < 4; u++)
#pragma unroll
            for (int k = 0; k < H; k++) acc[k] += w[u] * bfu2f((unsigned short)rv[u][k]);
    }
    for (; j < n; j++) {
        int s = (j < deg) ? csr[beg + j] : d;
        V rv = *(const V*)&hs[(size_t)s * (H * 64) + rowoff];
        float a = es[(size_t)s * H + hB] + edhB;
        a = (a > 0.0f) ? a : 0.2f * a;
        float w = expf(a - mB) * invB;
#pragma unroll
        for (int k = 0; k < H; k++) acc[k] += w * bfu2f((unsigned short)rv[k]);
    }
#pragma unroll
    for (int k = 0; k < H; k++) {
        float v = acc[k];
        if (ELU) {
            v += bias[lane * H + k];
            v = (v > 0.0f) ? v : expm1f(v);
        }
        acc[k] = v;
    }
    if constexpr (HOUT) {
        half8 hv;
#pragma unroll
        for (int k = 0; k < H; k++) hv[k] = (_Float16)acc[k];
        _Float16* op = (_Float16*)out + (size_t)d * (H * 64) + rowoff;
        *(half8*)op = hv;    // H==8 only
    } else {
        float* op = (float*)out + (size_t)d * (H * 64) + rowoff;
#pragma unroll
        for (int qd = 0; qd < H / 4; qd++)
            *(float4*)&op[qd * 4] = *(float4*)&acc[qd * 4];
    }
}

// ---------- final ----------
__global__ void final_kernel(const float* __restrict__ acc2, const float* __restrict__ bias2,
                             const float* __restrict__ fbuf, const float* __restrict__ flat_b,
                             const float* __restrict__ last, const float* __restrict__ outW,
                             const float* __restrict__ outb, float* __restrict__ out, int N) {
    int n = blockIdx.x * blockDim.x + threadIdx.x;
    if (n >= N) return;
    float s = outb[0];
    const float* a = acc2 + (size_t)n * 256;
    for (int c = 0; c < 64; c++) {
        float h2 = 0.25f * (a[c] + a[64 + c] + a[128 + c] + a[192 + c]) + bias2[c];
        s += h2 * outW[c];
        s += (fbuf[(size_t)n * 64 + c] + flat_b[c]) * outW[64 + c];
        s += last[(size_t)n * 64 + c] * outW[128 + c];
    }
    out[n] = s;
}

extern "C" void kernel_launch(void* const* d_in, const int* in_sizes, int n_in,
                              void* d_out, int out_size, void* d_ws, size_t ws_size,
                              hipStream_t stream) {
    const float* x    = (const float*)d_in[0];
    const float* flat = (const float*)d_in[1];
    const float* last = (const float*)d_in[2];
    const int*  es1i  = (const int*)d_in[3];
    const int*  ed1i  = (const int*)d_in[4];
    const int*  es2i  = (const int*)d_in[5];
    const int*  ed2i  = (const int*)d_in[6];
    const float* W1s  = (const float*)d_in[7];
    const float* W1d  = (const float*)d_in[8];
    const float* a1s  = (const float*)d_in[9];
    const float* a1d  = (const float*)d_in[10];
    const float* b1   = (const float*)d_in[11];
    const float* W2s  = (const float*)d_in[12];
    const float* W2d  = (const float*)d_in[13];
    const float* a2s  = (const float*)d_in[14];
    const float* a2d  = (const float*)d_in[15];
    const float* b2   = (const float*)d_in[16];
    const float* fW   = (const float*)d_in[17];
    const float* fb   = (const float*)d_in[18];
    const float* oW   = (const float*)d_in[19];
    const float* ob   = (const float*)d_in[20];
    float* out = (float*)d_out;

    float* ws = (float*)d_ws;
    // ---- layout (float-element offsets; proven footprint) ----
    unsigned short* hs1_bf = (unsigned short*)ws;                  // 40,960,000 us
    unsigned short* hd1_bf = (unsigned short*)(ws + 20480000);     //  8,192,000 us
    float* es1f = ws + 24576000;                                   // 640,000
    float* ed1f = ws + 25216000;                                   // 128,000
    float* acc1 = ws + 25344000;                                   // L1 out, fp16 [16000*512]
    unsigned short* wb = (unsigned short*)(ws + 54016000);
    unsigned short* w1s_pk = wb;                                   // 131072 us each (spaced 262144)
    unsigned short* w1d_pk = wb + 262144;
    unsigned short* w2s_pk = wb + 524288;
    unsigned short* w2d_pk = wb + 786432;
    unsigned short* fw_t3  = wb + 1048576;
    int* ibase   = (int*)(ws + 54816000);
    int* cnt1    = ibase;
    int* cursor1 = ibase + 16000;
    int* cnt2    = ibase + 32000;
    int* cursor2 = ibase + 36096;
    int* start1  = ibase + 40192;
    int* start2  = ibase + 56193;
    int* csr1    = ibase + 60290;
    int* csr2    = ibase + 316290;
    const size_t NEED = ((size_t)54816000 + 381826) * 4;
    if (ws_size < NEED) {
        fprintf(stderr, "kernel_launch: ws_size %zu < needed %zu\n", ws_size, NEED);
        return;
    }
    unsigned short* hs2_bf = (unsigned short*)ws;
    unsigned short* hd2_bf = (unsigned short*)(ws + 2048000);
    float* es2f = ws + 2572288;
    float* ed2f = ws + 2636288;
    float* acc2 = ws + 2652672;
    float* fbuf = ws + 3701248;
    unsigned short* acc1h = (unsigned short*)acc1;   // fp16 L1 output / L2 A

    // ---- prep (1 launch) + CSR build (3 launches) ----
    {
        int total = 262144 + 262144 + 8192 + 40192;
        prep_kernel<<<(total + 255) / 256, 256, 0, stream>>>(
            W1s, W1d, w1s_pk, w1d_pk,
            W2s, W2d, w2s_pk, w2d_pk,
            fW, fw_t3, ibase, 40192);
    }
    hist_dual<<<(E1 + E2 + 255) / 256, 256, 0, stream>>>(ed1i, cnt1, ed2i, cnt2);
    scan_dual<<<2, 1024, 0, stream>>>(cnt1, start1, N2, cnt2, start2, N3);
    fill_dual<<<(E1 + E2 + 255) / 256, 256, 0, stream>>>(
        es1i, ed1i, start1, cursor1, csr1, es2i, ed2i, start2, cursor2, csr2);

    // ---- layer 1: src+dst GEMMs in one grid (LDS-shared fp16 A, K-step 64) ----
    {
        const int MT = N1 / 64 + N2 / 64;   // 1250 + 250 = 1500 M-panels
        const int NB = 512 / 256;           // 2 column-blocks
        const int grid = 8 * NB * ((MT + 7) / 8);
        gemm_lds<false><<<grid, 256, 0, stream>>>(
            x, w1s_pk, hs1_bf, a1s, es1f,
            w1d_pk, hd1_bf, a1d, ed1f,
            N1 / 64, MT, NB, 512, 256, 8);
    }
    gat_agg2<8, true, true><<<N2 / 4, 256, 0, stream>>>(
        csr1, start1, hs1_bf, es1f, ed1f, b1, acc1h, N2);

    // ---- layer 2: src+dst GEMMs in one grid (A = fp16 from agg1) ----
    {
        const int MT = N2 / 64 + N3 / 64;   // 250 + 64 = 314
        const int NB = 1;
        const int grid = 8 * NB * ((MT + 7) / 8);
        gemm_lds<true><<<grid, 256, 0, stream>>>(
            acc1h, w2s_pk, hs2_bf, a2s, es2f,
            w2d_pk, hd2_bf, a2d, ed2f,
            N2 / 64, MT, NB, 256, 512, 4);
    }
    gat_agg2<4, false, false><<<N3 / 4, 256, 0, stream>>>(
        csr2, start2, hs2_bf, es2f, ed2f, nullptr, acc2, N3);

    // ---- flat MLP + output ----
    gemm_mfma<<<dim3(1, N3 / 64), 256, 0, stream>>>(flat, fw_t3, fbuf, N3, 64, 128);
    final_kernel<<<(N3 + 255) / 256, 256, 0, stream>>>(acc2, b2, fbuf, fb, last, oW, ob, out, N3);
}